// Round 5
// baseline (25017.499 us; speedup 1.0000x reference)
//
#include <hip/hip_runtime.h>
#include <hip/hip_bf16.h>

#define TDIM 4096
#define BDIM 64
#define FDIM 128
#define HDIM 512
#define ODIM 128
#define KWIN 32

typedef __attribute__((ext_vector_type(8))) short short8;
typedef __attribute__((ext_vector_type(4))) float floatx4;
typedef __attribute__((ext_vector_type(4))) float float4v;
typedef __attribute__((ext_vector_type(4))) int int4v;
typedef __attribute__((ext_vector_type(2))) unsigned int uint2v;

__device__ __forceinline__ unsigned short f2bf(float f) {
  unsigned int u = __float_as_uint(f);
  u += 0x7fffu + ((u >> 16) & 1u);
  return (unsigned short)(u >> 16);
}
__device__ __forceinline__ unsigned int cvt_pk_bf16(float lo, float hi) {
  unsigned int r;
  asm("v_cvt_pk_bf16_f32 %0, %1, %2" : "=v"(r) : "v"(lo), "v"(hi));
  return r;
}
__device__ __forceinline__ int4v g_load16_cc(const void* p) {
  int4v r;
  asm volatile("global_load_dwordx4 %0, %1, off sc0 sc1"
               : "=&v"(r) : "v"(p) : "memory");
  return r;
}
__device__ __forceinline__ uint2v g_load8_cc(const void* p) {
  uint2v r;
  asm volatile("global_load_dwordx2 %0, %1, off sc0 sc1\n\ts_waitcnt vmcnt(0)"
               : "=&v"(r) : "v"(p) : "memory");
  return r;
}
__device__ __forceinline__ unsigned int g_load4_cc(const void* p) {
  unsigned int r;
  asm volatile("global_load_dword %0, %1, off sc0 sc1\n\ts_waitcnt vmcnt(0)"
               : "=&v"(r) : "v"(p) : "memory");
  return r;
}
__device__ __forceinline__ void g_store4_cc(void* p, unsigned int v) {
  asm volatile("global_store_dword %0, %1, off sc0 sc1"
               :: "v"(p), "v"(v) : "memory");
}
// tanh of 4 pre-activations (already scaled by 2/ln2), packed to 4 i8 bytes.
__device__ __forceinline__ unsigned int tanh_pack4(float p0, float p1, float p2, float p3) {
  float r0 = __builtin_amdgcn_rcpf(exp2f(p0) + 1.0f);
  float r1 = __builtin_amdgcn_rcpf(exp2f(p1) + 1.0f);
  float r2 = __builtin_amdgcn_rcpf(exp2f(p2) + 1.0f);
  float r3 = __builtin_amdgcn_rcpf(exp2f(p3) + 1.0f);
  // q = rint(127 - 254 r) in low byte via magic 1.5*2^23 (12582912): 127+magic
  unsigned int f0 = __float_as_uint(fmaf(r0, -254.0f, 12583039.0f));
  unsigned int f1 = __float_as_uint(fmaf(r1, -254.0f, 12583039.0f));
  unsigned int f2 = __float_as_uint(fmaf(r2, -254.0f, 12583039.0f));
  unsigned int f3 = __float_as_uint(fmaf(r3, -254.0f, 12583039.0f));
  unsigned int t0 = __builtin_amdgcn_perm(f1, f0, 0x0C0C0400u);
  unsigned int t1 = __builtin_amdgcn_perm(f3, f2, 0x0C0C0400u);
  return __builtin_amdgcn_perm(t1, t0, 0x05040100u);
}

// ---------------------------------------------------------------------------
// Prep: frac-diff + input projection (as R3/R4) but stores pre*(2/ln2).
// xp dword idx = t*16384 + g*4096 + ((w*4+mt)*2+pr)*64 + l  (w in [0,8))
// value = C2 * pre[batch=g*16+(l&15)][hcol=w*64+mt*16+(l>>4)*4+2*pr+{0,1}]
// ---------------------------------------------------------------------------
__global__ __launch_bounds__(512, 1)
void prep_kernel(const float* __restrict__ x, const float* __restrict__ bd,
                 const float* __restrict__ Wih, const float* __restrict__ bih,
                 const float* __restrict__ bhh, unsigned int* __restrict__ xp)
{
  __shared__ float wpi[33 * 128];
  __shared__ __align__(16) float xslab[2][48 * 128];
  __shared__ __align__(16) short xf[256 * 136];

  const int tid = threadIdx.x;
  const int tc = blockIdx.x;
  const int g  = blockIdx.y;
  const int t0 = tc * 16;
  const float C2 = 2.885390081777927f;   // 2/ln2

  if (tid < 128) {
    float d = 0.5f / (1.0f + __expf(-bd[tid]));
    float pi = 1.0f;
    wpi[tid] = pi;
    for (int i = 0; i < 32; ++i) {
      pi *= ((float)i - d) / (float)(i + 1);
      wpi[(i + 1) * 128 + tid] = pi;
    }
  }

  {
    int bb = g * 16;
    #pragma unroll
    for (int rep = 0; rep < 3; ++rep) {
      int flat = rep * 512 + tid;
      int row = flat >> 5, c4 = flat & 31;
      int t = t0 + row - 32;
      float4v v = {0.f, 0.f, 0.f, 0.f};
      if (t >= 0) v = *(const float4v*)(x + ((size_t)t * BDIM + bb) * FDIM + (size_t)c4 * 4);
      *(float4v*)&xslab[0][row * 128 + c4 * 4] = v;
    }
  }
  __syncthreads();

  const int f = tid & 127, tl = tid >> 7;
  float wv[33];
  #pragma unroll
  for (int j = 0; j < 33; ++j) wv[j] = wpi[j * 128 + f];

  for (int bloc = 0; bloc < 16; ++bloc) {
    int cur = bloc & 1;
    float4v tmp[3];
    if (bloc < 15) {
      int bb = g * 16 + bloc + 1;
      #pragma unroll
      for (int rep = 0; rep < 3; ++rep) {
        int flat = rep * 512 + tid;
        int row = flat >> 5, c4 = flat & 31;
        int t = t0 + row - 32;
        float4v v = {0.f, 0.f, 0.f, 0.f};
        if (t >= 0) v = *(const float4v*)(x + ((size_t)t * BDIM + bb) * FDIM + (size_t)c4 * 4);
        tmp[rep] = v;
      }
    }
    #pragma unroll
    for (int s = 0; s < 4; ++s) {
      int tloc = tl * 4 + s;
      float acc = 0.f;
      #pragma unroll
      for (int j = 0; j < 33; ++j) acc += wv[j] * xslab[cur][(tloc + 32 - j) * 128 + f];
      xf[(tloc * 16 + bloc) * 136 + f] = (short)f2bf(acc);
    }
    if (bloc < 15) {
      #pragma unroll
      for (int rep = 0; rep < 3; ++rep) {
        int flat = rep * 512 + tid;
        int row = flat >> 5, c4 = flat & 31;
        *(float4v*)&xslab[cur ^ 1][row * 128 + c4 * 4] = tmp[rep];
      }
    }
    __syncthreads();
  }

  const int w = tid >> 6, l = tid & 63;
  const int lr = l & 15, lq = l >> 4;

  short8 wf[4][4];
  float4v bias4[4];
  #pragma unroll
  for (int mt = 0; mt < 4; ++mt) {
    #pragma unroll
    for (int kc = 0; kc < 4; ++kc) {
      int hcol = w * 64 + mt * 16 + lr;
      const float* src = Wih + (size_t)hcol * FDIM + kc * 32 + lq * 8;
      float4v f0 = *(const float4v*)src;
      float4v f1 = *(const float4v*)(src + 4);
      short8 s;
      s[0] = (short)f2bf(f0[0]); s[1] = (short)f2bf(f0[1]);
      s[2] = (short)f2bf(f0[2]); s[3] = (short)f2bf(f0[3]);
      s[4] = (short)f2bf(f1[0]); s[5] = (short)f2bf(f1[1]);
      s[6] = (short)f2bf(f1[2]); s[7] = (short)f2bf(f1[3]);
      wf[mt][kc] = s;
    }
    int hb = w * 64 + mt * 16 + lq * 4;
    float4v b0 = *(const float4v*)(bih + hb);
    float4v b1 = *(const float4v*)(bhh + hb);
    bias4[mt] = b0 + b1;
  }

  #pragma unroll
  for (int ntile = 0; ntile < 16; ++ntile) {
    floatx4 acc[4];
    #pragma unroll
    for (int kc = 0; kc < 4; ++kc) {
      short8 b = *(const short8*)&xf[(ntile * 16 + lr) * 136 + kc * 32 + lq * 8];
      #pragma unroll
      for (int mt = 0; mt < 4; ++mt) {
        floatx4 c = (kc == 0) ? (floatx4){0.f, 0.f, 0.f, 0.f} : acc[mt];
        acc[mt] = __builtin_amdgcn_mfma_f32_16x16x32_bf16(wf[mt][kc], b, c, 0, 0, 0);
      }
    }
    int t = t0 + ntile;
    #pragma unroll
    for (int mt = 0; mt < 4; ++mt) {
      float4v s = (acc[mt] + bias4[mt]) * C2;
      unsigned int d0 = cvt_pk_bf16(s[0], s[1]);
      unsigned int d1 = cvt_pk_bf16(s[2], s[3]);
      size_t base = (size_t)t * 16384 + (size_t)(g * 4096) + (size_t)((w * 4 + mt) * 2) * 64 + l;
      xp[base] = d0;
      xp[base + 64] = d1;
    }
  }
}

// ---------------------------------------------------------------------------
// Scan, 2-way H-split. Active WGs: bid<4 -> (half0,g=bid); 8<=bid<12 ->
// (half1,g=bid-8)  (bid & bid+8 land on the same XCD under %8 round-robin).
// Each WG owns 256 hcols; per-step 4KB h-half exchange via dead xp slots
// with sc0sc1 (MALL-coherent) accesses; flags (0x5AFE0000|t) live in d_out
// dwords later overwritten by the epilogue's real outputs.
// h(u) slot: u<=1 -> slot 0 (prep's xp(0), fully consumed pre-flag(0)),
// else slot u.  Numerics identical to R4 (exact i32 accumulation).
// ---------------------------------------------------------------------------
__global__ __launch_bounds__(512, 2)
void scan_kernel(const float* __restrict__ Whh, unsigned int* __restrict__ xp,
                 const float* __restrict__ Who, const float* __restrict__ bho,
                 float* __restrict__ out)
{
  const int bid = blockIdx.x;
  if ((bid >= 4 && bid < 8) || bid >= 12) return;
  const int half = bid >> 3;
  const int g = bid & 3;
  const int peer = 1 - half;

  __shared__ __align__(16) unsigned char h8[2][16 * 544];  // [buf][batch][col 512+pad]
  __shared__ float smax[8][2][16];
  __shared__ __align__(16) short hbf[16 * 520];

  const int tid = threadIdx.x;
  const int ws = tid >> 6, l = tid & 63;
  const int lr = l & 15, lq = l >> 4;
  const float C2 = 2.885390081777927f;

  const int hbase = half * 256 + (ws >> 1) * 64 + (ws & 1) * 32;  // +mtl*16
  const int colloc = (ws >> 1) * 64 + (ws & 1) * 32 + lq * 4;     // +mtl*16, within half

  // ---- per-row |max| of W_hh ----
  float rmax[2];
  #pragma unroll
  for (int mtl = 0; mtl < 2; ++mtl) {
    const float* row = Whh + (size_t)(hbase + mtl * 16 + lr) * HDIM + lq * 128;
    float m = 0.f;
    #pragma unroll 8
    for (int j = 0; j < 128; j += 4) {
      float4v v = *(const float4v*)(row + j);
      m = fmaxf(m, fmaxf(fmaxf(fabsf(v[0]), fabsf(v[1])), fmaxf(fabsf(v[2]), fabsf(v[3]))));
    }
    m = fmaxf(m, __shfl_xor(m, 16));
    m = fmaxf(m, __shfl_xor(m, 32));
    rmax[mtl] = fmaxf(m, 1e-20f);
    if (lq == 0) smax[ws][mtl][lr] = rmax[mtl];
  }

  // ---- quantize W fragments (A operand): lane k = kc*64 + lq*16 + 0..15 ----
  int4v wq[8][2];
  #pragma unroll
  for (int mtl = 0; mtl < 2; ++mtl) {
    float qs = 127.0f / rmax[mtl];
    #pragma unroll
    for (int kc = 0; kc < 8; ++kc) {
      const float* src = Whh + (size_t)(hbase + mtl * 16 + lr) * HDIM + kc * 64 + lq * 16;
      int4v d;
      #pragma unroll
      for (int dw = 0; dw < 4; ++dw) {
        float4v v = *(const float4v*)(src + dw * 4);
        int b0 = (int)__builtin_rintf(v[0] * qs);
        int b1 = (int)__builtin_rintf(v[1] * qs);
        int b2 = (int)__builtin_rintf(v[2] * qs);
        int b3 = (int)__builtin_rintf(v[3] * qs);
        d[dw] = (b0 & 255) | ((b1 & 255) << 8) | ((b2 & 255) << 16) | (b3 << 24);
      }
      wq[kc][mtl] = d;
    }
  }

  // ---- pointers ----
  const char* xpc = (const char*)xp;
  char* xpm = (char*)xp;
  unsigned int* fown  = (unsigned int*)out + g * 2048 + half;
  unsigned int* fpeer = (unsigned int*)out + g * 2048 + peer;
  const size_t segb = (size_t)g * 16384;
  const int xoff = g * 4096 + ((ws >> 1) * 8 + (ws & 1) * 4) * 64 + l;  // + hf*2048 + mtl*128 + pr*64

  // ---- bootstrap: h(0) = tanh(xp(0)) full-width, local ----
  unsigned int ucur[4];
  {
    #pragma unroll
    for (int hf = 0; hf < 2; ++hf) {
      unsigned int u0 = xp[xoff + hf * 2048];
      unsigned int u1 = xp[xoff + hf * 2048 + 64];
      unsigned int u2 = xp[xoff + hf * 2048 + 128];
      unsigned int u3 = xp[xoff + hf * 2048 + 192];
      unsigned int pk0 = tanh_pack4(__uint_as_float(u0 << 16), __uint_as_float(u0 & 0xffff0000u),
                                    __uint_as_float(u1 << 16), __uint_as_float(u1 & 0xffff0000u));
      unsigned int pk1 = tanh_pack4(__uint_as_float(u2 << 16), __uint_as_float(u2 & 0xffff0000u),
                                    __uint_as_float(u3 << 16), __uint_as_float(u3 & 0xffff0000u));
      *(unsigned int*)&h8[0][lr * 544 + hf * 256 + colloc] = pk0;
      *(unsigned int*)&h8[0][lr * 544 + hf * 256 + colloc + 16] = pk1;
    }
    // prefetch xp(1)
    const unsigned int* q = xp + (size_t)16384 + xoff + half * 2048;
    ucur[0] = q[0]; ucur[1] = q[128]; ucur[2] = q[64]; ucur[3] = q[192];
    // ucur order: [mtl*2+pr]: mtl0pr0, mtl1pr0? fix below -> use [mtl*2+pr]
  }
  // reorder to [mtl*2+pr] = {0:mtl0pr0, 1:mtl0pr1, 2:mtl1pr0, 3:mtl1pr1}
  { unsigned int a = ucur[1], b = ucur[2]; ucur[1] = b; ucur[2] = a; }  // now 1=+64(pr1), 2=+128(mtl1)
  __syncthreads();

  float sc2[2][4];
  #pragma unroll
  for (int mtl = 0; mtl < 2; ++mtl)
    #pragma unroll
    for (int r = 0; r < 4; ++r)
      sc2[mtl][r] = smax[ws][mtl][lq * 4 + r] * (C2 / 16129.0f);

  if (tid == 0) g_store4_cc(fown, 0x5AFE0000u);  // flag(0): our slot-0 reads done

  const int ownk = half * 4, peerk = peer * 4;
  const int4v zero4 = {0, 0, 0, 0};

  #pragma unroll 1
  for (int t = 1; t < TDIM; ++t) {
    const int p = (t - 1) & 1;
    // spin for peer h(t-1) ready (t==1: guards only our slot-0 write)
    {
      unsigned int tgt = 0x5AFE0000u | (unsigned int)(t - 1);
      while (g_load4_cc(fpeer) != tgt) __builtin_amdgcn_s_sleep(2);
    }
    // prefetch xp(t+1) (plain; prep data, read-only)
    unsigned int unext[4];
    if (t < TDIM - 1) {
      const unsigned int* q = xp + (size_t)(t + 1) * 16384 + xoff + half * 2048;
      unext[0] = q[0]; unext[1] = q[64]; unext[2] = q[128]; unext[3] = q[192];
    }
    // peer-B loads (h(t-1) peer half) from its slot
    int4v pb0, pb1, pb2, pb3;
    if (t >= 2) {
      size_t slot = (size_t)((t - 1 <= 1) ? 0 : (t - 1)) * 65536;
      const char* pbase = xpc + slot + segb + (size_t)peer * 4096 + lr * 256 + lq * 16;
      pb0 = g_load16_cc(pbase);
      pb1 = g_load16_cc(pbase + 64);
      pb2 = g_load16_cc(pbase + 128);
      pb3 = g_load16_cc(pbase + 192);
    }
    // MFMA own-half kc from LDS
    int4v acc0 = zero4, acc1 = zero4;
    #pragma unroll
    for (int kcl = 0; kcl < 4; ++kcl) {
      int kc = ownk + kcl;
      int4v b = *(const int4v*)&h8[p][lr * 544 + kc * 64 + lq * 16];
      acc0 = __builtin_amdgcn_mfma_i32_16x16x64_i8(wq[kc][0], b, acc0, 0, 0, 0);
      acc1 = __builtin_amdgcn_mfma_i32_16x16x64_i8(wq[kc][1], b, acc1, 0, 0, 0);
    }
    // MFMA peer-half kc
    if (t >= 2) {
      asm volatile("s_waitcnt vmcnt(0)" ::: "memory");
      __builtin_amdgcn_sched_barrier(0);
      acc0 = __builtin_amdgcn_mfma_i32_16x16x64_i8(wq[peerk][0], pb0, acc0, 0, 0, 0);
      acc1 = __builtin_amdgcn_mfma_i32_16x16x64_i8(wq[peerk][1], pb0, acc1, 0, 0, 0);
      acc0 = __builtin_amdgcn_mfma_i32_16x16x64_i8(wq[peerk + 1][0], pb1, acc0, 0, 0, 0);
      acc1 = __builtin_amdgcn_mfma_i32_16x16x64_i8(wq[peerk + 1][1], pb1, acc1, 0, 0, 0);
      acc0 = __builtin_amdgcn_mfma_i32_16x16x64_i8(wq[peerk + 2][0], pb2, acc0, 0, 0, 0);
      acc1 = __builtin_amdgcn_mfma_i32_16x16x64_i8(wq[peerk + 2][1], pb2, acc1, 0, 0, 0);
      acc0 = __builtin_amdgcn_mfma_i32_16x16x64_i8(wq[peerk + 3][0], pb3, acc0, 0, 0, 0);
      acc1 = __builtin_amdgcn_mfma_i32_16x16x64_i8(wq[peerk + 3][1], pb3, acc1, 0, 0, 0);
    } else {
      #pragma unroll
      for (int kcl = 0; kcl < 4; ++kcl) {
        int kc = peerk + kcl;
        int4v b = *(const int4v*)&h8[p][lr * 544 + kc * 64 + lq * 16];
        acc0 = __builtin_amdgcn_mfma_i32_16x16x64_i8(wq[kc][0], b, acc0, 0, 0, 0);
        acc1 = __builtin_amdgcn_mfma_i32_16x16x64_i8(wq[kc][1], b, acc1, 0, 0, 0);
      }
    }
    // tanh + pack (acc row r = hcol hbase+mtl*16+lq*4+r, batch lr)
    unsigned int pk0, pk1;
    {
      unsigned int ua = ucur[0], ub = ucur[1];
      pk0 = tanh_pack4((float)acc0[0] * sc2[0][0] + __uint_as_float(ua << 16),
                       (float)acc0[1] * sc2[0][1] + __uint_as_float(ua & 0xffff0000u),
                       (float)acc0[2] * sc2[0][2] + __uint_as_float(ub << 16),
                       (float)acc0[3] * sc2[0][3] + __uint_as_float(ub & 0xffff0000u));
      ua = ucur[2]; ub = ucur[3];
      pk1 = tanh_pack4((float)acc1[0] * sc2[1][0] + __uint_as_float(ua << 16),
                       (float)acc1[1] * sc2[1][1] + __uint_as_float(ua & 0xffff0000u),
                       (float)acc1[2] * sc2[1][2] + __uint_as_float(ub << 16),
                       (float)acc1[3] * sc2[1][3] + __uint_as_float(ub & 0xffff0000u));
    }
    // LDS own-half write (next buf)
    *(unsigned int*)&h8[p ^ 1][lr * 544 + half * 256 + colloc] = pk0;
    *(unsigned int*)&h8[p ^ 1][lr * 544 + half * 256 + colloc + 16] = pk1;
    // global h store into slot_of(t)
    {
      size_t slot = (size_t)((t <= 1) ? 0 : t) * 65536;
      char* hb = xpm + slot + segb + (size_t)half * 4096 + lr * 256 + colloc;
      g_store4_cc(hb, pk0);
      g_store4_cc(hb + 16, pk1);
    }
    asm volatile("s_waitcnt vmcnt(0)" ::: "memory");
    __syncthreads();
    if (tid == 0) g_store4_cc(fown, 0x5AFE0000u | (unsigned int)t);
    ucur[0] = unext[0]; ucur[1] = unext[1]; ucur[2] = unext[2]; ucur[3] = unext[3];
  }

  // ---- epilogue: final exchange of h(4095) (in buf 1) ----
  {
    unsigned int tgt = 0x5AFE0000u | 4095u;
    while (g_load4_cc(fpeer) != tgt) __builtin_amdgcn_s_sleep(2);
    int row = tid >> 5, dw = tid & 31;
    const char* pb = xpc + (size_t)4095 * 65536 + segb + (size_t)peer * 4096 + row * 256 + dw * 8;
    uint2v v = g_load8_cc(pb);
    *(uint2v*)&h8[1][row * 544 + peer * 256 + dw * 8] = v;
  }
  __syncthreads();
  if (tid == 0) g_store4_cc(fown, 0x5AFE0000u | 4096u);   // ack: past final spin
  if (half == 0) {
    while (g_load4_cc(fpeer) != (0x5AFE0000u | 4096u)) __builtin_amdgcn_s_sleep(2);
  }

  // bf16 h for projection; half1 writes hT
  for (int i = tid; i < 16 * 512; i += 512) {
    int row = i >> 9, col = i & 511;
    float f = (float)((signed char)h8[1][row * 544 + col]) * (1.0f / 127.0f);
    hbf[row * 520 + col] = (short)f2bf(f);
    if (half == 1)
      out[(size_t)ODIM * BDIM + ((size_t)(g * 16 + row)) * HDIM + col] = f;
  }
  __syncthreads();

  if (half == 0) {
    // outputs = h @ Who^T + bho; wave ws covers o = ws*16 + lr
    floatx4 oacc;
    #pragma unroll
    for (int kc = 0; kc < 16; ++kc) {
      short8 a = *(const short8*)&hbf[lr * 520 + kc * 32 + lq * 8];
      int o = ws * 16 + lr;
      const float* src = Who + (size_t)o * HDIM + kc * 32 + lq * 8;
      float4v f0 = *(const float4v*)src;
      float4v f1 = *(const float4v*)(src + 4);
      short8 s;
      s[0] = (short)f2bf(f0[0]); s[1] = (short)f2bf(f0[1]);
      s[2] = (short)f2bf(f0[2]); s[3] = (short)f2bf(f0[3]);
      s[4] = (short)f2bf(f1[0]); s[5] = (short)f2bf(f1[1]);
      s[6] = (short)f2bf(f1[2]); s[7] = (short)f2bf(f1[3]);
      floatx4 c = (kc == 0) ? (floatx4){0.f, 0.f, 0.f, 0.f} : oacc;
      oacc = __builtin_amdgcn_mfma_f32_16x16x32_bf16(a, s, c, 0, 0, 0);
    }
    #pragma unroll
    for (int rr = 0; rr < 4; ++rr) {
      int o = ws * 16 + lr;
      int row = lq * 4 + rr;
      out[((size_t)(g * 16 + row)) * ODIM + o] = oacc[rr] + bho[o];
    }
  }
}

// ---------------------------------------------------------------------------
extern "C" void kernel_launch(void* const* d_in, const int* in_sizes, int n_in,
                              void* d_out, int out_size, void* d_ws, size_t ws_size,
                              hipStream_t stream) {
  const float* x   = (const float*)d_in[0];
  const float* bd  = (const float*)d_in[1];
  const float* Wih = (const float*)d_in[2];
  const float* bih = (const float*)d_in[3];
  const float* Whh = (const float*)d_in[4];
  const float* bhh = (const float*)d_in[5];
  const float* Who = (const float*)d_in[6];
  const float* bho = (const float*)d_in[7];
  float* out = (float*)d_out;
  unsigned int* xp = (unsigned int*)d_ws;   // T*B*H*2 = 256 MiB exactly

  prep_kernel<<<dim3(TDIM / 16, 4), 512, 0, stream>>>(x, bd, Wih, bih, bhh, xp);
  scan_kernel<<<dim3(16), 512, 0, stream>>>(Whh, xp, Who, bho, out);
}

// Round 7
// 4438.383 us; speedup vs baseline: 5.6366x; 5.6366x over previous
//
#include <hip/hip_runtime.h>
#include <hip/hip_bf16.h>

#define TDIM 4096
#define BDIM 64
#define FDIM 128
#define HDIM 512
#define ODIM 128
#define KWIN 32

typedef __attribute__((ext_vector_type(8))) short short8;
typedef __attribute__((ext_vector_type(4))) float floatx4;
typedef __attribute__((ext_vector_type(4))) float float4v;
typedef __attribute__((ext_vector_type(4))) int int4v;

__device__ __forceinline__ unsigned short f2bf(float f) {
  unsigned int u = __float_as_uint(f);
  u += 0x7fffu + ((u >> 16) & 1u);
  return (unsigned short)(u >> 16);
}
__device__ __forceinline__ unsigned int cvt_pk_bf16(float lo, float hi) {
  unsigned int r;
  asm("v_cvt_pk_bf16_f32 %0, %1, %2" : "=v"(r) : "v"(lo), "v"(hi));
  return r;
}
// row_shr:8 — lane i reads lane i-8 within each 16-lane row.
// Lanes (lane%16)<8 have no source -> keep `old` (bound_ctrl=false).
// So: lanes lr<8 keep old (their own acc[0/1]); lanes lr>=8 take src
// (acc[2/3]) from lane lr-8 (same batch = lr&7).
__device__ __forceinline__ int dpp_takehi(int old, int src) {
  return __builtin_amdgcn_update_dpp(old, src, 0x118 /*row_shr:8*/, 0xF, 0xF, false);
}
// tanh of 4 pre-activations (already scaled by 2/ln2), packed to 4 i8 bytes.
__device__ __forceinline__ unsigned int tanh_pack4(float p0, float p1, float p2, float p3) {
  float r0 = __builtin_amdgcn_rcpf(exp2f(p0) + 1.0f);
  float r1 = __builtin_amdgcn_rcpf(exp2f(p1) + 1.0f);
  float r2 = __builtin_amdgcn_rcpf(exp2f(p2) + 1.0f);
  float r3 = __builtin_amdgcn_rcpf(exp2f(p3) + 1.0f);
  // q = rint(127 - 254 r) in low byte via magic 1.5*2^23: 12582912 + 127
  unsigned int f0 = __float_as_uint(fmaf(r0, -254.0f, 12583039.0f));
  unsigned int f1 = __float_as_uint(fmaf(r1, -254.0f, 12583039.0f));
  unsigned int f2 = __float_as_uint(fmaf(r2, -254.0f, 12583039.0f));
  unsigned int f3 = __float_as_uint(fmaf(r3, -254.0f, 12583039.0f));
  unsigned int t0 = __builtin_amdgcn_perm(f1, f0, 0x0C0C0400u);
  unsigned int t1 = __builtin_amdgcn_perm(f3, f2, 0x0C0C0400u);
  return __builtin_amdgcn_perm(t1, t0, 0x05040100u);
}

// ---------------------------------------------------------------------------
// Prep: frac-diff + input projection; stores pre*(2/ln2) in the 8-batch scan
// layout. For scan WG gg (batches gg*8..+7), wave ws, lane l (lq=l>>4,
// lr=l&15), slot s in 0..3 (s = mtp*2 + pr, mtEff = (lr>=8?2:0)+mtp):
//   dword idx = t*16384 + gg*2048 + ws*256 + s*64 + l
//   value = C2*pre[batch=gg*8+(lr&7)][hcol=ws*64+mtEff*16+lq*4+pr*2+{0,1}]
// ---------------------------------------------------------------------------
__global__ __launch_bounds__(512, 1)
void prep_kernel(const float* __restrict__ x, const float* __restrict__ bd,
                 const float* __restrict__ Wih, const float* __restrict__ bih,
                 const float* __restrict__ bhh, unsigned int* __restrict__ xp)
{
  __shared__ float wpi[33 * 128];
  __shared__ __align__(16) float xslab[2][48 * 128];
  __shared__ __align__(16) short xf[256 * 136];

  const int tid = threadIdx.x;
  const int tc = blockIdx.x;
  const int g  = blockIdx.y;          // 16-batch group 0..3
  const int t0 = tc * 16;
  const float C2 = 2.885390081777927f;   // 2/ln2

  if (tid < 128) {
    float d = 0.5f / (1.0f + __expf(-bd[tid]));
    float pi = 1.0f;
    wpi[tid] = pi;
    for (int i = 0; i < 32; ++i) {
      pi *= ((float)i - d) / (float)(i + 1);
      wpi[(i + 1) * 128 + tid] = pi;
    }
  }

  {
    int bb = g * 16;
    #pragma unroll
    for (int rep = 0; rep < 3; ++rep) {
      int flat = rep * 512 + tid;
      int row = flat >> 5, c4 = flat & 31;
      int t = t0 + row - 32;
      float4v v = {0.f, 0.f, 0.f, 0.f};
      if (t >= 0) v = *(const float4v*)(x + ((size_t)t * BDIM + bb) * FDIM + (size_t)c4 * 4);
      *(float4v*)&xslab[0][row * 128 + c4 * 4] = v;
    }
  }
  __syncthreads();

  const int f = tid & 127, tl = tid >> 7;
  float wv[33];
  #pragma unroll
  for (int j = 0; j < 33; ++j) wv[j] = wpi[j * 128 + f];

  for (int bloc = 0; bloc < 16; ++bloc) {
    int cur = bloc & 1;
    float4v tmp[3];
    if (bloc < 15) {
      int bb = g * 16 + bloc + 1;
      #pragma unroll
      for (int rep = 0; rep < 3; ++rep) {
        int flat = rep * 512 + tid;
        int row = flat >> 5, c4 = flat & 31;
        int t = t0 + row - 32;
        float4v v = {0.f, 0.f, 0.f, 0.f};
        if (t >= 0) v = *(const float4v*)(x + ((size_t)t * BDIM + bb) * FDIM + (size_t)c4 * 4);
        tmp[rep] = v;
      }
    }
    #pragma unroll
    for (int s = 0; s < 4; ++s) {
      int tloc = tl * 4 + s;
      float acc = 0.f;
      #pragma unroll
      for (int j = 0; j < 33; ++j) acc += wv[j] * xslab[cur][(tloc + 32 - j) * 128 + f];
      xf[(tloc * 16 + bloc) * 136 + f] = (short)f2bf(acc);
    }
    if (bloc < 15) {
      #pragma unroll
      for (int rep = 0; rep < 3; ++rep) {
        int flat = rep * 512 + tid;
        int row = flat >> 5, c4 = flat & 31;
        *(float4v*)&xslab[cur ^ 1][row * 128 + c4 * 4] = tmp[rep];
      }
    }
    __syncthreads();
  }

  const int w = tid >> 6, l = tid & 63;
  const int lr = l & 15, lq = l >> 4;

  short8 wf[4][4];
  float4v bias4[4];
  #pragma unroll
  for (int mt = 0; mt < 4; ++mt) {
    #pragma unroll
    for (int kc = 0; kc < 4; ++kc) {
      int hcol = w * 64 + mt * 16 + lr;
      const float* src = Wih + (size_t)hcol * FDIM + kc * 32 + lq * 8;
      float4v f0 = *(const float4v*)src;
      float4v f1 = *(const float4v*)(src + 4);
      short8 s;
      s[0] = (short)f2bf(f0[0]); s[1] = (short)f2bf(f0[1]);
      s[2] = (short)f2bf(f0[2]); s[3] = (short)f2bf(f0[3]);
      s[4] = (short)f2bf(f1[0]); s[5] = (short)f2bf(f1[1]);
      s[6] = (short)f2bf(f1[2]); s[7] = (short)f2bf(f1[3]);
      wf[mt][kc] = s;
    }
    int hb = w * 64 + mt * 16 + lq * 4;
    float4v b0 = *(const float4v*)(bih + hb);
    float4v b1 = *(const float4v*)(bhh + hb);
    bias4[mt] = b0 + b1;
  }

  #pragma unroll
  for (int ntile = 0; ntile < 16; ++ntile) {
    floatx4 acc[4];
    #pragma unroll
    for (int kc = 0; kc < 4; ++kc) {
      short8 b = *(const short8*)&xf[(ntile * 16 + lr) * 136 + kc * 32 + lq * 8];
      #pragma unroll
      for (int mt = 0; mt < 4; ++mt) {
        floatx4 c = (kc == 0) ? (floatx4){0.f, 0.f, 0.f, 0.f} : acc[mt];
        acc[mt] = __builtin_amdgcn_mfma_f32_16x16x32_bf16(wf[mt][kc], b, c, 0, 0, 0);
      }
    }
    int t = t0 + ntile;
    #pragma unroll
    for (int mt = 0; mt < 4; ++mt) {
      float4v s = (acc[mt] + bias4[mt]) * C2;
      unsigned int d0 = cvt_pk_bf16(s[0], s[1]);
      unsigned int d1 = cvt_pk_bf16(s[2], s[3]);
      int gg = g * 2 + (lr >> 3);
      int lp = lq * 16 + ((mt >> 1) * 8) + (lr & 7);
      size_t base = (size_t)t * 16384 + (size_t)(gg * 2048 + w * 256 + ((mt & 1) * 2) * 64 + lp);
      xp[base] = d0;          // pr=0: hcols lq*4+0,1
      xp[base + 64] = d1;     // pr=1: hcols lq*4+2,3
    }
  }
}

// ---------------------------------------------------------------------------
// Scan: 8 WGs (batch groups of 8) x 512 threads (8 waves, 2/SIMD).
// W_hh i8 per-row-scale, register/AGPR-resident. h in i8 LDS (rows 0..7
// valid, 8..15 stay zero), double-buffered, ONE barrier/step.
// MFMA D[hcol][batch]: valid batch cols 0..7; DPP row_shr:8 redistributes
// the mt=2,3 accumulators to lanes lr>=8 so all 64 lanes share the tanh
// (8 elems/lane instead of 16 on half the lanes).
// ---------------------------------------------------------------------------
__global__ __launch_bounds__(512, 2)
void scan_kernel(const float* __restrict__ Whh, const unsigned int* __restrict__ xp,
                 const float* __restrict__ Who, const float* __restrict__ bho,
                 float* __restrict__ out)
{
  __shared__ __align__(16) unsigned char h8[2][16 * 544];  // [buf][brow][col 512+pad]
  __shared__ float smax[8][4][16];
  __shared__ __align__(16) short hbf[16 * 520];

  const int tid = threadIdx.x;
  const int gg = blockIdx.x;                // batches gg*8 .. gg*8+7
  const int ws = tid >> 6, l = tid & 63;
  const int lr = l & 15, lq = l >> 4;
  const float C2 = 2.885390081777927f;

  // ---- per-row |max| of W_hh (wave ws owns hcols ws*64..+63) ----
  float rmax[4];
  #pragma unroll
  for (int mt = 0; mt < 4; ++mt) {
    const float* row = Whh + (size_t)(ws * 64 + mt * 16 + lr) * HDIM + lq * 128;
    float m = 0.f;
    #pragma unroll 8
    for (int j = 0; j < 128; j += 4) {
      float4v v = *(const float4v*)(row + j);
      m = fmaxf(m, fmaxf(fmaxf(fabsf(v[0]), fabsf(v[1])), fmaxf(fabsf(v[2]), fabsf(v[3]))));
    }
    m = fmaxf(m, __shfl_xor(m, 16));
    m = fmaxf(m, __shfl_xor(m, 32));
    rmax[mt] = fmaxf(m, 1e-20f);
    if (lq == 0) smax[ws][mt][lr] = rmax[mt];
  }

  // ---- quantize W fragments (A operand): lane k = kc*64 + lq*16 + 0..15 ----
  int4v wq[8][4];
  #pragma unroll
  for (int mt = 0; mt < 4; ++mt) {
    float qs = 127.0f / rmax[mt];
    #pragma unroll
    for (int kc = 0; kc < 8; ++kc) {
      const float* src = Whh + (size_t)(ws * 64 + mt * 16 + lr) * HDIM + kc * 64 + lq * 16;
      int4v d;
      #pragma unroll
      for (int dw = 0; dw < 4; ++dw) {
        float4v v = *(const float4v*)(src + dw * 4);
        int b0 = (int)__builtin_rintf(v[0] * qs);
        int b1 = (int)__builtin_rintf(v[1] * qs);
        int b2 = (int)__builtin_rintf(v[2] * qs);
        int b3 = (int)__builtin_rintf(v[3] * qs);
        d[dw] = (b0 & 255) | ((b1 & 255) << 8) | ((b2 & 255) << 16) | (b3 << 24);
      }
      wq[kc][mt] = d;
    }
  }

  for (int i = tid; i < 2 * 16 * 544 / 4; i += 512) ((int*)h8)[i] = 0;
  __syncthreads();

  // ---- per-lane dequant scales (lane-half picks mt high bit) ----
  const int mthi = (lr >> 3) * 2;
  float sc2[2][4];
  #pragma unroll
  for (int mtp = 0; mtp < 2; ++mtp)
    #pragma unroll
    for (int r = 0; r < 4; ++r)
      sc2[mtp][r] = smax[ws][mthi + mtp][lq * 4 + r] * (C2 / 16129.0f);

  const unsigned int* xpb = xp + (size_t)(gg * 2048 + ws * 256 + l);
  const int wrow = (lr & 7) * 544;
  const int col0 = ws * 64 + mthi * 16 + lq * 4;

  // ---- bootstrap: h(after xp(0)) = tanh(xp(0)) into buf0; prefetch xp(1) ----
  unsigned int u[4];
  u[0] = xpb[0]; u[1] = xpb[64]; u[2] = xpb[128]; u[3] = xpb[192];
  {
    unsigned int pk0 = tanh_pack4(__uint_as_float(u[0] << 16), __uint_as_float(u[0] & 0xffff0000u),
                                  __uint_as_float(u[1] << 16), __uint_as_float(u[1] & 0xffff0000u));
    unsigned int pk1 = tanh_pack4(__uint_as_float(u[2] << 16), __uint_as_float(u[2] & 0xffff0000u),
                                  __uint_as_float(u[3] << 16), __uint_as_float(u[3] & 0xffff0000u));
    *(unsigned int*)&h8[0][wrow + col0] = pk0;
    *(unsigned int*)&h8[0][wrow + col0 + 16] = pk1;
  }
  {
    const unsigned int* q = xpb + 16384;
    u[0] = q[0]; u[1] = q[64]; u[2] = q[128]; u[3] = q[192];
  }
  __syncthreads();

  const int4v zero4 = {0, 0, 0, 0};

  #pragma unroll 1
  for (int t = 1; t < TDIM; ++t) {
    const int p = (t - 1) & 1;
    // prefetch xp(t+1)
    unsigned int un[4];
    if (t < TDIM - 1) {
      const unsigned int* q = xpb + (size_t)(t + 1) * 16384;
      un[0] = q[0]; un[1] = q[64]; un[2] = q[128]; un[3] = q[192];
    }
    // ---- W . h : 32 MFMA (batch cols 0..7 valid; 8..15 are zeros) ----
    int4v acc[4];
    #pragma unroll
    for (int mt = 0; mt < 4; ++mt) acc[mt] = zero4;
    #pragma unroll
    for (int kc = 0; kc < 8; ++kc) {
      int4v b = *(const int4v*)&h8[p][lr * 544 + kc * 64 + lq * 16];
      #pragma unroll
      for (int mt = 0; mt < 4; ++mt)
        acc[mt] = __builtin_amdgcn_mfma_i32_16x16x64_i8(wq[kc][mt], b, acc[mt], 0, 0, 0);
    }
    // ---- DPP redistribute: lanes lr>=8 take mt=2,3 from lane lr-8 ----
    int4v ap0, ap1;
    #pragma unroll
    for (int d = 0; d < 4; ++d) {
      ap0[d] = dpp_takehi(acc[0][d], acc[2][d]);
      ap1[d] = dpp_takehi(acc[1][d], acc[3][d]);
    }
    // ---- dequant + xp + tanh + pack (8 elems/lane) ----
    unsigned int pk0, pk1;
    pk0 = tanh_pack4((float)ap0[0] * sc2[0][0] + __uint_as_float(u[0] << 16),
                     (float)ap0[1] * sc2[0][1] + __uint_as_float(u[0] & 0xffff0000u),
                     (float)ap0[2] * sc2[0][2] + __uint_as_float(u[1] << 16),
                     (float)ap0[3] * sc2[0][3] + __uint_as_float(u[1] & 0xffff0000u));
    pk1 = tanh_pack4((float)ap1[0] * sc2[1][0] + __uint_as_float(u[2] << 16),
                     (float)ap1[1] * sc2[1][1] + __uint_as_float(u[2] & 0xffff0000u),
                     (float)ap1[2] * sc2[1][2] + __uint_as_float(u[3] << 16),
                     (float)ap1[3] * sc2[1][3] + __uint_as_float(u[3] & 0xffff0000u));
    *(unsigned int*)&h8[p ^ 1][wrow + col0] = pk0;
    *(unsigned int*)&h8[p ^ 1][wrow + col0 + 16] = pk1;
    __syncthreads();
    u[0] = un[0]; u[1] = un[1]; u[2] = un[2]; u[3] = un[3];
  }
  // final h (after xp(4095)) is in buf 1

  // ---- hT (output 1) + bf16 h for projection (rows 8..15 are zeros) ----
  for (int i = tid; i < 16 * 512; i += 512) {
    int row = i >> 9, col = i & 511;
    float f = (float)((signed char)h8[1][row * 544 + col]) * (1.0f / 127.0f);
    hbf[row * 520 + col] = (short)f2bf(f);
    if (row < 8)
      out[(size_t)ODIM * BDIM + ((size_t)(gg * 8 + row)) * HDIM + col] = f;
  }
  __syncthreads();

  // ---- output projection: D[batch][o] = h[batch][:] . Who[o][:] ----
  floatx4 oacc;
  #pragma unroll
  for (int kc = 0; kc < 16; ++kc) {
    short8 a = *(const short8*)&hbf[lr * 520 + kc * 32 + lq * 8];
    int o = ws * 16 + lr;
    const float* src = Who + (size_t)o * HDIM + kc * 32 + lq * 8;
    float4v f0 = *(const float4v*)src;
    float4v f1 = *(const float4v*)(src + 4);
    short8 s;
    s[0] = (short)f2bf(f0[0]); s[1] = (short)f2bf(f0[1]);
    s[2] = (short)f2bf(f0[2]); s[3] = (short)f2bf(f0[3]);
    s[4] = (short)f2bf(f1[0]); s[5] = (short)f2bf(f1[1]);
    s[6] = (short)f2bf(f1[2]); s[7] = (short)f2bf(f1[3]);
    floatx4 c = (kc == 0) ? (floatx4){0.f, 0.f, 0.f, 0.f} : oacc;
    oacc = __builtin_amdgcn_mfma_f32_16x16x32_bf16(a, s, c, 0, 0, 0);
  }
  #pragma unroll
  for (int rr = 0; rr < 4; ++rr) {
    int row = lq * 4 + rr;             // = batch within group; valid < 8
    if (row < 8) {
      int o = ws * 16 + lr;
      out[((size_t)(gg * 8 + row)) * ODIM + o] = oacc[rr] + bho[o];
    }
  }
}

// ---------------------------------------------------------------------------
extern "C" void kernel_launch(void* const* d_in, const int* in_sizes, int n_in,
                              void* d_out, int out_size, void* d_ws, size_t ws_size,
                              hipStream_t stream) {
  const float* x   = (const float*)d_in[0];
  const float* bd  = (const float*)d_in[1];
  const float* Wih = (const float*)d_in[2];
  const float* bih = (const float*)d_in[3];
  const float* Whh = (const float*)d_in[4];
  const float* bhh = (const float*)d_in[5];
  const float* Who = (const float*)d_in[6];
  const float* bho = (const float*)d_in[7];
  float* out = (float*)d_out;
  unsigned int* xp = (unsigned int*)d_ws;   // T*B*H*2 = 268.4 MB

  prep_kernel<<<dim3(TDIM / 16, 4), 512, 0, stream>>>(x, bd, Wih, bih, bhh, xp);
  scan_kernel<<<dim3(8), 512, 0, stream>>>(Whh, xp, Who, bho, out);
}

// Round 8
// 3459.529 us; speedup vs baseline: 7.2315x; 1.2829x over previous
//
#include <hip/hip_runtime.h>
#include <hip/hip_bf16.h>

#define TDIM 4096
#define BDIM 64
#define FDIM 128
#define HDIM 512
#define ODIM 128
#define KWIN 32

typedef __attribute__((ext_vector_type(8))) short short8;
typedef __attribute__((ext_vector_type(4))) float floatx4;
typedef __attribute__((ext_vector_type(4))) float float4v;
typedef __attribute__((ext_vector_type(4))) int int4v;

__device__ __forceinline__ unsigned short f2bf(float f) {
  unsigned int u = __float_as_uint(f);
  u += 0x7fffu + ((u >> 16) & 1u);
  return (unsigned short)(u >> 16);
}
__device__ __forceinline__ unsigned int cvt_pk_bf16(float lo, float hi) {
  unsigned int r;
  asm("v_cvt_pk_bf16_f32 %0, %1, %2" : "=v"(r) : "v"(lo), "v"(hi));
  return r;
}
// Overlay `src` shifted right by SHIFT lanes (within each 16-lane row) onto
// `old`, writing only the 4-lane banks in BANK (others keep old).
// row_shr:N ctrl = 0x110|N (verified R7: lane i reads lane i-N).
template <int CTRL, int BANK>
__device__ __forceinline__ int dpp_overlay(int old, int src) {
  return __builtin_amdgcn_update_dpp(old, src, CTRL, 0xF, BANK, false);
}
// tanh of 4 pre-activations (already scaled by 2/ln2), packed to 4 i8 bytes.
__device__ __forceinline__ unsigned int tanh_pack4(float p0, float p1, float p2, float p3) {
  float r0 = __builtin_amdgcn_rcpf(exp2f(p0) + 1.0f);
  float r1 = __builtin_amdgcn_rcpf(exp2f(p1) + 1.0f);
  float r2 = __builtin_amdgcn_rcpf(exp2f(p2) + 1.0f);
  float r3 = __builtin_amdgcn_rcpf(exp2f(p3) + 1.0f);
  // q = rint(127 - 254 r) in low byte via magic 1.5*2^23: 12582912 + 127
  unsigned int f0 = __float_as_uint(fmaf(r0, -254.0f, 12583039.0f));
  unsigned int f1 = __float_as_uint(fmaf(r1, -254.0f, 12583039.0f));
  unsigned int f2 = __float_as_uint(fmaf(r2, -254.0f, 12583039.0f));
  unsigned int f3 = __float_as_uint(fmaf(r3, -254.0f, 12583039.0f));
  unsigned int t0 = __builtin_amdgcn_perm(f1, f0, 0x0C0C0400u);
  unsigned int t1 = __builtin_amdgcn_perm(f3, f2, 0x0C0C0400u);
  return __builtin_amdgcn_perm(t1, t0, 0x05040100u);
}

// ---------------------------------------------------------------------------
// Prep: frac-diff + input projection; stores pre*(2/ln2) in the 16-WG scan
// layout. For scan WG gg (batches gg*4..+3), wave ws, lane l (lq=l>>4,
// lr=l&15, quad=lr>>2, bb=lr&3), pair pr:
//   dword idx = t*16384 + gg*1024 + ws*128 + pr*64 + l
//   value = C2*pre[batch=gg*4+bb][hcol = ws*64+quad*16+lq*4+pr*2+{0,1}]
// ---------------------------------------------------------------------------
__global__ __launch_bounds__(512, 1)
void prep_kernel(const float* __restrict__ x, const float* __restrict__ bd,
                 const float* __restrict__ Wih, const float* __restrict__ bih,
                 const float* __restrict__ bhh, unsigned int* __restrict__ xp)
{
  __shared__ float wpi[33 * 128];
  __shared__ __align__(16) float xslab[2][48 * 128];
  __shared__ __align__(16) short xf[256 * 136];

  const int tid = threadIdx.x;
  const int tc = blockIdx.x;
  const int g  = blockIdx.y;          // 16-batch group 0..3
  const int t0 = tc * 16;
  const float C2 = 2.885390081777927f;   // 2/ln2

  if (tid < 128) {
    float d = 0.5f / (1.0f + __expf(-bd[tid]));
    float pi = 1.0f;
    wpi[tid] = pi;
    for (int i = 0; i < 32; ++i) {
      pi *= ((float)i - d) / (float)(i + 1);
      wpi[(i + 1) * 128 + tid] = pi;
    }
  }

  {
    int bb = g * 16;
    #pragma unroll
    for (int rep = 0; rep < 3; ++rep) {
      int flat = rep * 512 + tid;
      int row = flat >> 5, c4 = flat & 31;
      int t = t0 + row - 32;
      float4v v = {0.f, 0.f, 0.f, 0.f};
      if (t >= 0) v = *(const float4v*)(x + ((size_t)t * BDIM + bb) * FDIM + (size_t)c4 * 4);
      *(float4v*)&xslab[0][row * 128 + c4 * 4] = v;
    }
  }
  __syncthreads();

  const int f = tid & 127, tl = tid >> 7;
  float wv[33];
  #pragma unroll
  for (int j = 0; j < 33; ++j) wv[j] = wpi[j * 128 + f];

  for (int bloc = 0; bloc < 16; ++bloc) {
    int cur = bloc & 1;
    float4v tmp[3];
    if (bloc < 15) {
      int bb = g * 16 + bloc + 1;
      #pragma unroll
      for (int rep = 0; rep < 3; ++rep) {
        int flat = rep * 512 + tid;
        int row = flat >> 5, c4 = flat & 31;
        int t = t0 + row - 32;
        float4v v = {0.f, 0.f, 0.f, 0.f};
        if (t >= 0) v = *(const float4v*)(x + ((size_t)t * BDIM + bb) * FDIM + (size_t)c4 * 4);
        tmp[rep] = v;
      }
    }
    #pragma unroll
    for (int s = 0; s < 4; ++s) {
      int tloc = tl * 4 + s;
      float acc = 0.f;
      #pragma unroll
      for (int j = 0; j < 33; ++j) acc += wv[j] * xslab[cur][(tloc + 32 - j) * 128 + f];
      xf[(tloc * 16 + bloc) * 136 + f] = (short)f2bf(acc);
    }
    if (bloc < 15) {
      #pragma unroll
      for (int rep = 0; rep < 3; ++rep) {
        int flat = rep * 512 + tid;
        int row = flat >> 5, c4 = flat & 31;
        *(float4v*)&xslab[cur ^ 1][row * 128 + c4 * 4] = tmp[rep];
      }
    }
    __syncthreads();
  }

  const int w = tid >> 6, l = tid & 63;
  const int lr = l & 15, lq = l >> 4;

  short8 wf[4][4];
  float4v bias4[4];
  #pragma unroll
  for (int mt = 0; mt < 4; ++mt) {
    #pragma unroll
    for (int kc = 0; kc < 4; ++kc) {
      int hcol = w * 64 + mt * 16 + lr;
      const float* src = Wih + (size_t)hcol * FDIM + kc * 32 + lq * 8;
      float4v f0 = *(const float4v*)src;
      float4v f1 = *(const float4v*)(src + 4);
      short8 s;
      s[0] = (short)f2bf(f0[0]); s[1] = (short)f2bf(f0[1]);
      s[2] = (short)f2bf(f0[2]); s[3] = (short)f2bf(f0[3]);
      s[4] = (short)f2bf(f1[0]); s[5] = (short)f2bf(f1[1]);
      s[6] = (short)f2bf(f1[2]); s[7] = (short)f2bf(f1[3]);
      wf[mt][kc] = s;
    }
    int hb = w * 64 + mt * 16 + lq * 4;
    float4v b0 = *(const float4v*)(bih + hb);
    float4v b1 = *(const float4v*)(bhh + hb);
    bias4[mt] = b0 + b1;
  }

  #pragma unroll
  for (int ntile = 0; ntile < 16; ++ntile) {
    floatx4 acc[4];
    #pragma unroll
    for (int kc = 0; kc < 4; ++kc) {
      short8 b = *(const short8*)&xf[(ntile * 16 + lr) * 136 + kc * 32 + lq * 8];
      #pragma unroll
      for (int mt = 0; mt < 4; ++mt) {
        floatx4 c = (kc == 0) ? (floatx4){0.f, 0.f, 0.f, 0.f} : acc[mt];
        acc[mt] = __builtin_amdgcn_mfma_f32_16x16x32_bf16(wf[mt][kc], b, c, 0, 0, 0);
      }
    }
    int t = t0 + ntile;
    #pragma unroll
    for (int mt = 0; mt < 4; ++mt) {
      float4v s = (acc[mt] + bias4[mt]) * C2;
      unsigned int d0 = cvt_pk_bf16(s[0], s[1]);
      unsigned int d1 = cvt_pk_bf16(s[2], s[3]);
      int gg2 = g * 4 + (lr >> 2);
      int lp  = lq * 16 + mt * 4 + (lr & 3);
      size_t base = (size_t)t * 16384 + (size_t)(gg2 * 1024 + w * 128 + lp);
      xp[base] = d0;          // pr=0: hcols lq*4+0,1
      xp[base + 64] = d1;     // pr=1: hcols lq*4+2,3
    }
  }
}

// ---------------------------------------------------------------------------
// Scan: 16 WGs (batch groups of 4) x 512 threads (8 waves, 2/SIMD).
// W_hh i8 per-row-scale, register-resident. h in i8 LDS with the B-frag-
// linear layout hN[kc][lq][batch][16B] (byte addr = kc*1024 + lane*16 for
// reads -> conflict-free ds_read_b128). Double-buffered, ONE barrier/step.
// DPP row_shr:{4,8,12} with bank_mask {0x2,0x4,0x8} redistributes the
// mt=1..3 accumulators to lane quadrants so all 64 lanes share the tanh
// (4 elems/lane).
// ---------------------------------------------------------------------------
__global__ __launch_bounds__(512, 2)
void scan_kernel(const float* __restrict__ Whh, const unsigned int* __restrict__ xp,
                 const float* __restrict__ Who, const float* __restrict__ bho,
                 float* __restrict__ out)
{
  __shared__ __align__(16) unsigned char hN[2][8192];  // [buf][kc*1024 + lane*16]
  __shared__ float smax[8][4][16];
  __shared__ __align__(16) short hbf[16 * 520];

  const int tid = threadIdx.x;
  const int gg = blockIdx.x;                // batches gg*4 .. gg*4+3
  const int ws = tid >> 6, l = tid & 63;
  const int lr = l & 15, lq = l >> 4;
  const int quad = lr >> 2, bb = lr & 3;
  const float C2 = 2.885390081777927f;

  // ---- per-row |max| of W_hh (wave ws owns hcols ws*64..+63) ----
  float rmax[4];
  #pragma unroll
  for (int mt = 0; mt < 4; ++mt) {
    const float* row = Whh + (size_t)(ws * 64 + mt * 16 + lr) * HDIM + lq * 128;
    float m = 0.f;
    #pragma unroll 8
    for (int j = 0; j < 128; j += 4) {
      float4v v = *(const float4v*)(row + j);
      m = fmaxf(m, fmaxf(fmaxf(fabsf(v[0]), fabsf(v[1])), fmaxf(fabsf(v[2]), fabsf(v[3]))));
    }
    m = fmaxf(m, __shfl_xor(m, 16));
    m = fmaxf(m, __shfl_xor(m, 32));
    rmax[mt] = fmaxf(m, 1e-20f);
    if (lq == 0) smax[ws][mt][lr] = rmax[mt];
  }

  // ---- quantize W fragments (A operand): lane k = kc*64 + lq*16 + 0..15 ----
  int4v wq[8][4];
  #pragma unroll
  for (int mt = 0; mt < 4; ++mt) {
    float qs = 127.0f / rmax[mt];
    #pragma unroll
    for (int kc = 0; kc < 8; ++kc) {
      const float* src = Whh + (size_t)(ws * 64 + mt * 16 + lr) * HDIM + kc * 64 + lq * 16;
      int4v d;
      #pragma unroll
      for (int dw = 0; dw < 4; ++dw) {
        float4v v = *(const float4v*)(src + dw * 4);
        int b0 = (int)__builtin_rintf(v[0] * qs);
        int b1 = (int)__builtin_rintf(v[1] * qs);
        int b2 = (int)__builtin_rintf(v[2] * qs);
        int b3 = (int)__builtin_rintf(v[3] * qs);
        d[dw] = (b0 & 255) | ((b1 & 255) << 8) | ((b2 & 255) << 16) | (b3 << 24);
      }
      wq[kc][mt] = d;
    }
  }

  for (int i = tid; i < 2 * 8192 / 4; i += 512) ((int*)hN)[i] = 0;
  __syncthreads();

  // ---- per-lane dequant scales: lane's quadrant picks mt = quad ----
  float sc[4];
  #pragma unroll
  for (int r = 0; r < 4; ++r)
    sc[r] = smax[ws][quad][lq * 4 + r] * (C2 / 16129.0f);

  const unsigned int* xpb = xp + (size_t)(gg * 1024 + ws * 128 + l);
  // write addr: h[batch=bb][k = ws*64 + quad*16 + lq*4 .. +3]
  const int waddr = ws * 1024 + quad * 256 + bb * 16 + lq * 4;

  // ---- bootstrap: h(after xp(0)) = tanh(xp(0)) into buf0; prefetch xp(1) ----
  unsigned int u0 = xpb[0], u1 = xpb[64];
  {
    unsigned int pk = tanh_pack4(__uint_as_float(u0 << 16), __uint_as_float(u0 & 0xffff0000u),
                                 __uint_as_float(u1 << 16), __uint_as_float(u1 & 0xffff0000u));
    *(unsigned int*)&hN[0][waddr] = pk;
  }
  u0 = xpb[16384]; u1 = xpb[16384 + 64];
  __syncthreads();

  const int4v zero4 = {0, 0, 0, 0};

  #pragma unroll 1
  for (int t = 1; t < TDIM; ++t) {
    const int p = (t - 1) & 1;
    // prefetch xp(t+1)
    unsigned int un0, un1;
    if (t < TDIM - 1) {
      const unsigned int* q = xpb + (size_t)(t + 1) * 16384;
      un0 = q[0]; un1 = q[64];
    }
    // ---- hoist all b-frags (conflict-free linear ds_read_b128) ----
    int4v bfr[8];
    #pragma unroll
    for (int kc = 0; kc < 8; ++kc)
      bfr[kc] = *(const int4v*)&hN[p][kc * 1024 + l * 16];
    // ---- W . h : 32 MFMA (batch cols 0..3 valid; rest zeros) ----
    int4v acc[4];
    #pragma unroll
    for (int mt = 0; mt < 4; ++mt) acc[mt] = zero4;
    #pragma unroll
    for (int kc = 0; kc < 8; ++kc)
      #pragma unroll
      for (int mt = 0; mt < 4; ++mt)
        acc[mt] = __builtin_amdgcn_mfma_i32_16x16x64_i8(wq[kc][mt], bfr[kc], acc[mt], 0, 0, 0);
    // ---- DPP redistribute: lane quadrant q takes acc[q] from lane lr-4q ----
    int4v ap;
    #pragma unroll
    for (int d = 0; d < 4; ++d) {
      int r = acc[0][d];
      r = dpp_overlay<0x114, 0x2>(r, acc[1][d]);   // row_shr:4  -> lanes 4..7
      r = dpp_overlay<0x118, 0x4>(r, acc[2][d]);   // row_shr:8  -> lanes 8..11
      r = dpp_overlay<0x11C, 0x8>(r, acc[3][d]);   // row_shr:12 -> lanes 12..15
      ap[d] = r;
    }
    // ---- dequant + xp + tanh + pack (4 elems/lane) ----
    unsigned int pk = tanh_pack4(
        (float)ap[0] * sc[0] + __uint_as_float(u0 << 16),
        (float)ap[1] * sc[1] + __uint_as_float(u0 & 0xffff0000u),
        (float)ap[2] * sc[2] + __uint_as_float(u1 << 16),
        (float)ap[3] * sc[3] + __uint_as_float(u1 & 0xffff0000u));
    *(unsigned int*)&hN[p ^ 1][waddr] = pk;
    __syncthreads();
    u0 = un0; u1 = un1;
  }
  // final h (after xp(4095)) is in buf 1

  // ---- hT (output 1) + bf16 h for projection (batch rows 0..3 valid) ----
  for (int i = tid; i < 16 * 512; i += 512) {
    int row = i >> 9, col = i & 511;
    float f = 0.f;
    if (row < 4) {
      int a = (col >> 6) * 1024 + ((col >> 4) & 3) * 256 + row * 16 + (col & 15);
      f = (float)((signed char)hN[1][a]) * (1.0f / 127.0f);
      out[(size_t)ODIM * BDIM + ((size_t)(gg * 4 + row)) * HDIM + col] = f;
    }
    hbf[row * 520 + col] = (short)f2bf(f);
  }
  __syncthreads();

  // ---- output projection: D[batch][o] = h[batch][:] . Who[o][:] ----
  floatx4 oacc;
  #pragma unroll
  for (int kc = 0; kc < 16; ++kc) {
    short8 a = *(const short8*)&hbf[lr * 520 + kc * 32 + lq * 8];
    int o = ws * 16 + lr;
    const float* src = Who + (size_t)o * HDIM + kc * 32 + lq * 8;
    float4v f0 = *(const float4v*)src;
    float4v f1 = *(const float4v*)(src + 4);
    short8 s;
    s[0] = (short)f2bf(f0[0]); s[1] = (short)f2bf(f0[1]);
    s[2] = (short)f2bf(f0[2]); s[3] = (short)f2bf(f0[3]);
    s[4] = (short)f2bf(f1[0]); s[5] = (short)f2bf(f1[1]);
    s[6] = (short)f2bf(f1[2]); s[7] = (short)f2bf(f1[3]);
    floatx4 c = (kc == 0) ? (floatx4){0.f, 0.f, 0.f, 0.f} : oacc;
    oacc = __builtin_amdgcn_mfma_f32_16x16x32_bf16(a, s, c, 0, 0, 0);
  }
  #pragma unroll
  for (int rr = 0; rr < 4; ++rr) {
    int row = lq * 4 + rr;             // = batch within group; valid < 4
    if (row < 4) {
      int o = ws * 16 + lr;
      out[((size_t)(gg * 4 + row)) * ODIM + o] = oacc[rr] + bho[o];
    }
  }
}

// ---------------------------------------------------------------------------
extern "C" void kernel_launch(void* const* d_in, const int* in_sizes, int n_in,
                              void* d_out, int out_size, void* d_ws, size_t ws_size,
                              hipStream_t stream) {
  const float* x   = (const float*)d_in[0];
  const float* bd  = (const float*)d_in[1];
  const float* Wih = (const float*)d_in[2];
  const float* bih = (const float*)d_in[3];
  const float* Whh = (const float*)d_in[4];
  const float* bhh = (const float*)d_in[5];
  const float* Who = (const float*)d_in[6];
  const float* bho = (const float*)d_in[7];
  float* out = (float*)d_out;
  unsigned int* xp = (unsigned int*)d_ws;   // T*B*H*2 = 268.4 MB

  prep_kernel<<<dim3(TDIM / 16, 4), 512, 0, stream>>>(x, bd, Wih, bih, bhh, xp);
  scan_kernel<<<dim3(16), 512, 0, stream>>>(Whh, xp, Who, bho, out);
}

// Round 9
// 3187.605 us; speedup vs baseline: 7.8484x; 1.0853x over previous
//
#include <hip/hip_runtime.h>
#include <hip/hip_bf16.h>

#define TDIM 4096
#define BDIM 64
#define FDIM 128
#define HDIM 512
#define ODIM 128
#define KWIN 32

typedef __attribute__((ext_vector_type(8))) short short8;
typedef __attribute__((ext_vector_type(4))) float floatx4;
typedef __attribute__((ext_vector_type(4))) float float4v;
typedef __attribute__((ext_vector_type(4))) int int4v;

__device__ __forceinline__ unsigned short f2bf(float f) {
  unsigned int u = __float_as_uint(f);
  u += 0x7fffu + ((u >> 16) & 1u);
  return (unsigned short)(u >> 16);
}
__device__ __forceinline__ unsigned int cvt_pk_bf16(float lo, float hi) {
  unsigned int r;
  asm("v_cvt_pk_bf16_f32 %0, %1, %2" : "=v"(r) : "v"(lo), "v"(hi));
  return r;
}
// Overlay `src` shifted right by N lanes (row_shr:N = 0x110|N; lane i reads
// lane i-N, verified R7/R8) onto `old`, only in 4-lane banks BANK.
template <int CTRL, int BANK>
__device__ __forceinline__ int dpp_overlay(int old, int src) {
  return __builtin_amdgcn_update_dpp(old, src, CTRL, 0xF, BANK, false);
}
// tanh of 4 pre-activations (already scaled by 2/ln2), packed to 4 i8 bytes.
__device__ __forceinline__ unsigned int tanh_pack4(float p0, float p1, float p2, float p3) {
  float r0 = __builtin_amdgcn_rcpf(exp2f(p0) + 1.0f);
  float r1 = __builtin_amdgcn_rcpf(exp2f(p1) + 1.0f);
  float r2 = __builtin_amdgcn_rcpf(exp2f(p2) + 1.0f);
  float r3 = __builtin_amdgcn_rcpf(exp2f(p3) + 1.0f);
  // q = rint(127 - 254 r) in low byte via magic 1.5*2^23: 12582912 + 127
  unsigned int f0 = __float_as_uint(fmaf(r0, -254.0f, 12583039.0f));
  unsigned int f1 = __float_as_uint(fmaf(r1, -254.0f, 12583039.0f));
  unsigned int f2 = __float_as_uint(fmaf(r2, -254.0f, 12583039.0f));
  unsigned int f3 = __float_as_uint(fmaf(r3, -254.0f, 12583039.0f));
  unsigned int t0 = __builtin_amdgcn_perm(f1, f0, 0x0C0C0400u);
  unsigned int t1 = __builtin_amdgcn_perm(f3, f2, 0x0C0C0400u);
  return __builtin_amdgcn_perm(t1, t0, 0x05040100u);
}

// ---------------------------------------------------------------------------
// Prep: frac-diff + input projection; stores pre*(2/ln2) in the 16-WG scan
// layout. For scan WG gg (batches gg*4..+3), wave ws, lane l (lq=l>>4,
// lr=l&15, quad=lr>>2, bb=lr&3), pair pr:
//   dword idx = t*16384 + gg*1024 + ws*128 + pr*64 + l
//   value = C2*pre[batch=gg*4+bb][hcol = ws*64+quad*16+lq*4+pr*2+{0,1}]
// ---------------------------------------------------------------------------
__global__ __launch_bounds__(512, 1)
void prep_kernel(const float* __restrict__ x, const float* __restrict__ bd,
                 const float* __restrict__ Wih, const float* __restrict__ bih,
                 const float* __restrict__ bhh, unsigned int* __restrict__ xp)
{
  __shared__ float wpi[33 * 128];
  __shared__ __align__(16) float xslab[2][48 * 128];
  __shared__ __align__(16) short xf[256 * 136];

  const int tid = threadIdx.x;
  const int tc = blockIdx.x;
  const int g  = blockIdx.y;          // 16-batch group 0..3
  const int t0 = tc * 16;
  const float C2 = 2.885390081777927f;   // 2/ln2

  if (tid < 128) {
    float d = 0.5f / (1.0f + __expf(-bd[tid]));
    float pi = 1.0f;
    wpi[tid] = pi;
    for (int i = 0; i < 32; ++i) {
      pi *= ((float)i - d) / (float)(i + 1);
      wpi[(i + 1) * 128 + tid] = pi;
    }
  }

  {
    int bb = g * 16;
    #pragma unroll
    for (int rep = 0; rep < 3; ++rep) {
      int flat = rep * 512 + tid;
      int row = flat >> 5, c4 = flat & 31;
      int t = t0 + row - 32;
      float4v v = {0.f, 0.f, 0.f, 0.f};
      if (t >= 0) v = *(const float4v*)(x + ((size_t)t * BDIM + bb) * FDIM + (size_t)c4 * 4);
      *(float4v*)&xslab[0][row * 128 + c4 * 4] = v;
    }
  }
  __syncthreads();

  const int f = tid & 127, tl = tid >> 7;
  float wv[33];
  #pragma unroll
  for (int j = 0; j < 33; ++j) wv[j] = wpi[j * 128 + f];

  for (int bloc = 0; bloc < 16; ++bloc) {
    int cur = bloc & 1;
    float4v tmp[3];
    if (bloc < 15) {
      int bb = g * 16 + bloc + 1;
      #pragma unroll
      for (int rep = 0; rep < 3; ++rep) {
        int flat = rep * 512 + tid;
        int row = flat >> 5, c4 = flat & 31;
        int t = t0 + row - 32;
        float4v v = {0.f, 0.f, 0.f, 0.f};
        if (t >= 0) v = *(const float4v*)(x + ((size_t)t * BDIM + bb) * FDIM + (size_t)c4 * 4);
        tmp[rep] = v;
      }
    }
    #pragma unroll
    for (int s = 0; s < 4; ++s) {
      int tloc = tl * 4 + s;
      float acc = 0.f;
      #pragma unroll
      for (int j = 0; j < 33; ++j) acc += wv[j] * xslab[cur][(tloc + 32 - j) * 128 + f];
      xf[(tloc * 16 + bloc) * 136 + f] = (short)f2bf(acc);
    }
    if (bloc < 15) {
      #pragma unroll
      for (int rep = 0; rep < 3; ++rep) {
        int flat = rep * 512 + tid;
        int row = flat >> 5, c4 = flat & 31;
        *(float4v*)&xslab[cur ^ 1][row * 128 + c4 * 4] = tmp[rep];
      }
    }
    __syncthreads();
  }

  const int w = tid >> 6, l = tid & 63;
  const int lr = l & 15, lq = l >> 4;

  short8 wf[4][4];
  float4v bias4[4];
  #pragma unroll
  for (int mt = 0; mt < 4; ++mt) {
    #pragma unroll
    for (int kc = 0; kc < 4; ++kc) {
      int hcol = w * 64 + mt * 16 + lr;
      const float* src = Wih + (size_t)hcol * FDIM + kc * 32 + lq * 8;
      float4v f0 = *(const float4v*)src;
      float4v f1 = *(const float4v*)(src + 4);
      short8 s;
      s[0] = (short)f2bf(f0[0]); s[1] = (short)f2bf(f0[1]);
      s[2] = (short)f2bf(f0[2]); s[3] = (short)f2bf(f0[3]);
      s[4] = (short)f2bf(f1[0]); s[5] = (short)f2bf(f1[1]);
      s[6] = (short)f2bf(f1[2]); s[7] = (short)f2bf(f1[3]);
      wf[mt][kc] = s;
    }
    int hb = w * 64 + mt * 16 + lq * 4;
    float4v b0 = *(const float4v*)(bih + hb);
    float4v b1 = *(const float4v*)(bhh + hb);
    bias4[mt] = b0 + b1;
  }

  #pragma unroll
  for (int ntile = 0; ntile < 16; ++ntile) {
    floatx4 acc[4];
    #pragma unroll
    for (int kc = 0; kc < 4; ++kc) {
      short8 b = *(const short8*)&xf[(ntile * 16 + lr) * 136 + kc * 32 + lq * 8];
      #pragma unroll
      for (int mt = 0; mt < 4; ++mt) {
        floatx4 c = (kc == 0) ? (floatx4){0.f, 0.f, 0.f, 0.f} : acc[mt];
        acc[mt] = __builtin_amdgcn_mfma_f32_16x16x32_bf16(wf[mt][kc], b, c, 0, 0, 0);
      }
    }
    int t = t0 + ntile;
    #pragma unroll
    for (int mt = 0; mt < 4; ++mt) {
      float4v s = (acc[mt] + bias4[mt]) * C2;
      unsigned int d0 = cvt_pk_bf16(s[0], s[1]);
      unsigned int d1 = cvt_pk_bf16(s[2], s[3]);
      int gg2 = g * 4 + (lr >> 2);
      int lp  = lq * 16 + mt * 4 + (lr & 3);
      size_t base = (size_t)t * 16384 + (size_t)(gg2 * 1024 + w * 128 + lp);
      xp[base] = d0;          // pr=0: hcols lq*4+0,1
      xp[base + 64] = d1;     // pr=1: hcols lq*4+2,3
    }
  }
}

// ---------------------------------------------------------------------------
// Scan: 16 WGs (batch groups of 4) x 512 threads (8 waves, 2/SIMD).
// W_hh i8 per-row-scale, register-resident. h in i8 LDS, B-frag-linear
// layout hN[buf][kc*1024 + lane*16] (conflict-free ds_read_b128).
// Double-buffered, ONE barrier/step; 2-step unroll makes both LDS buffer
// bases compile-time-static. DPP row_shr:{4,8,12} bank-masked redistributes
// mt=1..3 accumulators so all 64 lanes share the tanh (4 elems/lane).
// ---------------------------------------------------------------------------
__global__ __launch_bounds__(512, 2)
void scan_kernel(const float* __restrict__ Whh, const unsigned int* __restrict__ xp,
                 const float* __restrict__ Who, const float* __restrict__ bho,
                 float* __restrict__ out)
{
  __shared__ __align__(16) unsigned char hN[2][8192];  // [buf][kc*1024 + lane*16]
  __shared__ float smax[8][4][16];
  __shared__ __align__(16) short hbf[16 * 520];

  const int tid = threadIdx.x;
  const int gg = blockIdx.x;                // batches gg*4 .. gg*4+3
  const int ws = tid >> 6, l = tid & 63;
  const int lr = l & 15, lq = l >> 4;
  const int quad = lr >> 2, bb = lr & 3;
  const float C2 = 2.885390081777927f;

  // ---- per-row |max| of W_hh (wave ws owns hcols ws*64..+63) ----
  float rmax[4];
  #pragma unroll
  for (int mt = 0; mt < 4; ++mt) {
    const float* row = Whh + (size_t)(ws * 64 + mt * 16 + lr) * HDIM + lq * 128;
    float m = 0.f;
    #pragma unroll 8
    for (int j = 0; j < 128; j += 4) {
      float4v v = *(const float4v*)(row + j);
      m = fmaxf(m, fmaxf(fmaxf(fabsf(v[0]), fabsf(v[1])), fmaxf(fabsf(v[2]), fabsf(v[3]))));
    }
    m = fmaxf(m, __shfl_xor(m, 16));
    m = fmaxf(m, __shfl_xor(m, 32));
    rmax[mt] = fmaxf(m, 1e-20f);
    if (lq == 0) smax[ws][mt][lr] = rmax[mt];
  }

  // ---- quantize W fragments (A operand): lane k = kc*64 + lq*16 + 0..15 ----
  int4v wq[8][4];
  #pragma unroll
  for (int mt = 0; mt < 4; ++mt) {
    float qs = 127.0f / rmax[mt];
    #pragma unroll
    for (int kc = 0; kc < 8; ++kc) {
      const float* src = Whh + (size_t)(ws * 64 + mt * 16 + lr) * HDIM + kc * 64 + lq * 16;
      int4v d;
      #pragma unroll
      for (int dw = 0; dw < 4; ++dw) {
        float4v v = *(const float4v*)(src + dw * 4);
        int b0 = (int)__builtin_rintf(v[0] * qs);
        int b1 = (int)__builtin_rintf(v[1] * qs);
        int b2 = (int)__builtin_rintf(v[2] * qs);
        int b3 = (int)__builtin_rintf(v[3] * qs);
        d[dw] = (b0 & 255) | ((b1 & 255) << 8) | ((b2 & 255) << 16) | (b3 << 24);
      }
      wq[kc][mt] = d;
    }
  }

  for (int i = tid; i < 2 * 8192 / 4; i += 512) ((int*)hN)[i] = 0;
  __syncthreads();

  // ---- per-lane dequant scales: lane's quadrant picks mt = quad ----
  float sc[4];
  #pragma unroll
  for (int r = 0; r < 4; ++r)
    sc[r] = smax[ws][quad][lq * 4 + r] * (C2 / 16129.0f);

  const unsigned int* xpb = xp + (size_t)(gg * 1024 + ws * 128 + l);
  // write addr: h[batch=bb][k = ws*64 + quad*16 + lq*4 .. +3]
  const int waddr = ws * 1024 + quad * 256 + bb * 16 + lq * 4;

  // ---- bootstrap: h(after xp(0)) = tanh(xp(0)) into buf0; load xp(1) ----
  unsigned int u0 = xpb[0], u1 = xpb[64];
  {
    unsigned int pk = tanh_pack4(__uint_as_float(u0 << 16), __uint_as_float(u0 & 0xffff0000u),
                                 __uint_as_float(u1 << 16), __uint_as_float(u1 & 0xffff0000u));
    *(unsigned int*)&hN[0][waddr] = pk;
  }
  u0 = xpb[16384]; u1 = xpb[16384 + 64];
  __syncthreads();

  const int4v zero4 = {0, 0, 0, 0};
  const unsigned int* qp = xpb + (size_t)2 * 16384;   // running prefetch ptr

  // One recurrence step: read rb, write wb; consumes (u0,u1); if PF,
  // prefetches the next xp pair and advances qp.
  auto do_step = [&](const unsigned char* __restrict__ rb,
                     unsigned char* __restrict__ wb, bool pf) {
    unsigned int un0, un1;
    if (pf) { un0 = qp[0]; un1 = qp[64]; qp += 16384; }
    int4v bfr[8];
    #pragma unroll
    for (int kc = 0; kc < 8; ++kc)
      bfr[kc] = *(const int4v*)(rb + kc * 1024 + l * 16);
    int4v acc[4];
    #pragma unroll
    for (int mt = 0; mt < 4; ++mt) acc[mt] = zero4;
    #pragma unroll
    for (int kc = 0; kc < 8; ++kc)
      #pragma unroll
      for (int mt = 0; mt < 4; ++mt)
        acc[mt] = __builtin_amdgcn_mfma_i32_16x16x64_i8(wq[kc][mt], bfr[kc], acc[mt], 0, 0, 0);
    int4v ap;
    #pragma unroll
    for (int d = 0; d < 4; ++d) {
      int r = acc[0][d];
      r = dpp_overlay<0x114, 0x2>(r, acc[1][d]);   // row_shr:4  -> lanes 4..7
      r = dpp_overlay<0x118, 0x4>(r, acc[2][d]);   // row_shr:8  -> lanes 8..11
      r = dpp_overlay<0x11C, 0x8>(r, acc[3][d]);   // row_shr:12 -> lanes 12..15
      ap[d] = r;
    }
    unsigned int pk = tanh_pack4(
        (float)ap[0] * sc[0] + __uint_as_float(u0 << 16),
        (float)ap[1] * sc[1] + __uint_as_float(u0 & 0xffff0000u),
        (float)ap[2] * sc[2] + __uint_as_float(u1 << 16),
        (float)ap[3] * sc[3] + __uint_as_float(u1 & 0xffff0000u));
    *(unsigned int*)(wb + waddr) = pk;
    __syncthreads();
    if (pf) { u0 = un0; u1 = un1; }
  };

  // steps t=1..4094 in pairs (static buffers), tail t=4095 (no prefetch)
  #pragma unroll 1
  for (int t = 1; t <= TDIM - 3; t += 2) {
    do_step(hN[0], hN[1], true);
    do_step(hN[1], hN[0], true);
  }
  do_step(hN[0], hN[1], false);
  // final h (after xp(4095)) is in buf 1

  // ---- hT (output 1) + bf16 h for projection (batch rows 0..3 valid) ----
  for (int i = tid; i < 16 * 512; i += 512) {
    int row = i >> 9, col = i & 511;
    float f = 0.f;
    if (row < 4) {
      int a = (col >> 6) * 1024 + ((col >> 4) & 3) * 256 + row * 16 + (col & 15);
      f = (float)((signed char)hN[1][a]) * (1.0f / 127.0f);
      out[(size_t)ODIM * BDIM + ((size_t)(gg * 4 + row)) * HDIM + col] = f;
    }
    hbf[row * 520 + col] = (short)f2bf(f);
  }
  __syncthreads();

  // ---- output projection: D[batch][o] = h[batch][:] . Who[o][:] ----
  floatx4 oacc;
  #pragma unroll
  for (int kc = 0; kc < 16; ++kc) {
    short8 a = *(const short8*)&hbf[lr * 520 + kc * 32 + lq * 8];
    int o = ws * 16 + lr;
    const float* src = Who + (size_t)o * HDIM + kc * 32 + lq * 8;
    float4v f0 = *(const float4v*)src;
    float4v f1 = *(const float4v*)(src + 4);
    short8 s;
    s[0] = (short)f2bf(f0[0]); s[1] = (short)f2bf(f0[1]);
    s[2] = (short)f2bf(f0[2]); s[3] = (short)f2bf(f0[3]);
    s[4] = (short)f2bf(f1[0]); s[5] = (short)f2bf(f1[1]);
    s[6] = (short)f2bf(f1[2]); s[7] = (short)f2bf(f1[3]);
    floatx4 c = (kc == 0) ? (floatx4){0.f, 0.f, 0.f, 0.f} : oacc;
    oacc = __builtin_amdgcn_mfma_f32_16x16x32_bf16(a, s, c, 0, 0, 0);
  }
  #pragma unroll
  for (int rr = 0; rr < 4; ++rr) {
    int row = lq * 4 + rr;             // = batch within group; valid < 4
    if (row < 4) {
      int o = ws * 16 + lr;
      out[((size_t)(gg * 4 + row)) * ODIM + o] = oacc[rr] + bho[o];
    }
  }
}

// ---------------------------------------------------------------------------
extern "C" void kernel_launch(void* const* d_in, const int* in_sizes, int n_in,
                              void* d_out, int out_size, void* d_ws, size_t ws_size,
                              hipStream_t stream) {
  const float* x   = (const float*)d_in[0];
  const float* bd  = (const float*)d_in[1];
  const float* Wih = (const float*)d_in[2];
  const float* bih = (const float*)d_in[3];
  const float* Whh = (const float*)d_in[4];
  const float* bhh = (const float*)d_in[5];
  const float* Who = (const float*)d_in[6];
  const float* bho = (const float*)d_in[7];
  float* out = (float*)d_out;
  unsigned int* xp = (unsigned int*)d_ws;   // T*B*H*2 = 268.4 MB

  prep_kernel<<<dim3(TDIM / 16, 4), 512, 0, stream>>>(x, bd, Wih, bih, bhh, xp);
  scan_kernel<<<dim3(16), 512, 0, stream>>>(Whh, xp, Who, bho, out);
}

// Round 10
// 3144.383 us; speedup vs baseline: 7.9562x; 1.0137x over previous
//
#include <hip/hip_runtime.h>
#include <hip/hip_bf16.h>

#define TDIM 4096
#define BDIM 64
#define FDIM 128
#define HDIM 512
#define ODIM 128
#define KWIN 32

typedef __attribute__((ext_vector_type(8))) short short8;
typedef __attribute__((ext_vector_type(4))) float floatx4;
typedef __attribute__((ext_vector_type(4))) float float4v;
typedef __attribute__((ext_vector_type(4))) int int4v;

__device__ __forceinline__ unsigned short f2bf(float f) {
  unsigned int u = __float_as_uint(f);
  u += 0x7fffu + ((u >> 16) & 1u);
  return (unsigned short)(u >> 16);
}
__device__ __forceinline__ unsigned int cvt_pk_bf16(float lo, float hi) {
  unsigned int r;
  asm("v_cvt_pk_bf16_f32 %0, %1, %2" : "=v"(r) : "v"(lo), "v"(hi));
  return r;
}
// Overlay `src` shifted right by N lanes (row_shr:N = 0x110|N; lane i reads
// lane i-N, verified R7/R8) onto `old`, only in 4-lane banks BANK.
template <int CTRL, int BANK>
__device__ __forceinline__ int dpp_overlay(int old, int src) {
  return __builtin_amdgcn_update_dpp(old, src, CTRL, 0xF, BANK, false);
}
// tanh of 4 pre-activations (already scaled by 2/ln2), packed to 4 i8 bytes.
__device__ __forceinline__ unsigned int tanh_pack4(float p0, float p1, float p2, float p3) {
  float r0 = __builtin_amdgcn_rcpf(exp2f(p0) + 1.0f);
  float r1 = __builtin_amdgcn_rcpf(exp2f(p1) + 1.0f);
  float r2 = __builtin_amdgcn_rcpf(exp2f(p2) + 1.0f);
  float r3 = __builtin_amdgcn_rcpf(exp2f(p3) + 1.0f);
  // q = rint(127 - 254 r) in low byte via magic 1.5*2^23: 12582912 + 127
  unsigned int f0 = __float_as_uint(fmaf(r0, -254.0f, 12583039.0f));
  unsigned int f1 = __float_as_uint(fmaf(r1, -254.0f, 12583039.0f));
  unsigned int f2 = __float_as_uint(fmaf(r2, -254.0f, 12583039.0f));
  unsigned int f3 = __float_as_uint(fmaf(r3, -254.0f, 12583039.0f));
  unsigned int t0 = __builtin_amdgcn_perm(f1, f0, 0x0C0C0400u);
  unsigned int t1 = __builtin_amdgcn_perm(f3, f2, 0x0C0C0400u);
  return __builtin_amdgcn_perm(t1, t0, 0x05040100u);
}

// ---------------------------------------------------------------------------
// Prep: frac-diff + input projection; stores pre*(2/ln2) in the 16-WG scan
// layout. For scan WG gg (batches gg*4..+3), wave ws, lane l (lq=l>>4,
// lr=l&15, quad=lr>>2, bb=lr&3), pair pr:
//   dword idx = t*16384 + gg*1024 + ws*128 + pr*64 + l
//   value = C2*pre[batch=gg*4+bb][hcol = ws*64+quad*16+lq*4+pr*2+{0,1}]
// ---------------------------------------------------------------------------
__global__ __launch_bounds__(512, 1)
void prep_kernel(const float* __restrict__ x, const float* __restrict__ bd,
                 const float* __restrict__ Wih, const float* __restrict__ bih,
                 const float* __restrict__ bhh, unsigned int* __restrict__ xp)
{
  __shared__ float wpi[33 * 128];
  __shared__ __align__(16) float xslab[2][48 * 128];
  __shared__ __align__(16) short xf[256 * 136];

  const int tid = threadIdx.x;
  const int tc = blockIdx.x;
  const int g  = blockIdx.y;          // 16-batch group 0..3
  const int t0 = tc * 16;
  const float C2 = 2.885390081777927f;   // 2/ln2

  if (tid < 128) {
    float d = 0.5f / (1.0f + __expf(-bd[tid]));
    float pi = 1.0f;
    wpi[tid] = pi;
    for (int i = 0; i < 32; ++i) {
      pi *= ((float)i - d) / (float)(i + 1);
      wpi[(i + 1) * 128 + tid] = pi;
    }
  }

  {
    int bb = g * 16;
    #pragma unroll
    for (int rep = 0; rep < 3; ++rep) {
      int flat = rep * 512 + tid;
      int row = flat >> 5, c4 = flat & 31;
      int t = t0 + row - 32;
      float4v v = {0.f, 0.f, 0.f, 0.f};
      if (t >= 0) v = *(const float4v*)(x + ((size_t)t * BDIM + bb) * FDIM + (size_t)c4 * 4);
      *(float4v*)&xslab[0][row * 128 + c4 * 4] = v;
    }
  }
  __syncthreads();

  const int f = tid & 127, tl = tid >> 7;
  float wv[33];
  #pragma unroll
  for (int j = 0; j < 33; ++j) wv[j] = wpi[j * 128 + f];

  for (int bloc = 0; bloc < 16; ++bloc) {
    int cur = bloc & 1;
    float4v tmp[3];
    if (bloc < 15) {
      int bb = g * 16 + bloc + 1;
      #pragma unroll
      for (int rep = 0; rep < 3; ++rep) {
        int flat = rep * 512 + tid;
        int row = flat >> 5, c4 = flat & 31;
        int t = t0 + row - 32;
        float4v v = {0.f, 0.f, 0.f, 0.f};
        if (t >= 0) v = *(const float4v*)(x + ((size_t)t * BDIM + bb) * FDIM + (size_t)c4 * 4);
        tmp[rep] = v;
      }
    }
    #pragma unroll
    for (int s = 0; s < 4; ++s) {
      int tloc = tl * 4 + s;
      float acc = 0.f;
      #pragma unroll
      for (int j = 0; j < 33; ++j) acc += wv[j] * xslab[cur][(tloc + 32 - j) * 128 + f];
      xf[(tloc * 16 + bloc) * 136 + f] = (short)f2bf(acc);
    }
    if (bloc < 15) {
      #pragma unroll
      for (int rep = 0; rep < 3; ++rep) {
        int flat = rep * 512 + tid;
        int row = flat >> 5, c4 = flat & 31;
        *(float4v*)&xslab[cur ^ 1][row * 128 + c4 * 4] = tmp[rep];
      }
    }
    __syncthreads();
  }

  const int w = tid >> 6, l = tid & 63;
  const int lr = l & 15, lq = l >> 4;

  short8 wf[4][4];
  float4v bias4[4];
  #pragma unroll
  for (int mt = 0; mt < 4; ++mt) {
    #pragma unroll
    for (int kc = 0; kc < 4; ++kc) {
      int hcol = w * 64 + mt * 16 + lr;
      const float* src = Wih + (size_t)hcol * FDIM + kc * 32 + lq * 8;
      float4v f0 = *(const float4v*)src;
      float4v f1 = *(const float4v*)(src + 4);
      short8 s;
      s[0] = (short)f2bf(f0[0]); s[1] = (short)f2bf(f0[1]);
      s[2] = (short)f2bf(f0[2]); s[3] = (short)f2bf(f0[3]);
      s[4] = (short)f2bf(f1[0]); s[5] = (short)f2bf(f1[1]);
      s[6] = (short)f2bf(f1[2]); s[7] = (short)f2bf(f1[3]);
      wf[mt][kc] = s;
    }
    int hb = w * 64 + mt * 16 + lq * 4;
    float4v b0 = *(const float4v*)(bih + hb);
    float4v b1 = *(const float4v*)(bhh + hb);
    bias4[mt] = b0 + b1;
  }

  #pragma unroll
  for (int ntile = 0; ntile < 16; ++ntile) {
    floatx4 acc[4];
    #pragma unroll
    for (int kc = 0; kc < 4; ++kc) {
      short8 b = *(const short8*)&xf[(ntile * 16 + lr) * 136 + kc * 32 + lq * 8];
      #pragma unroll
      for (int mt = 0; mt < 4; ++mt) {
        floatx4 c = (kc == 0) ? (floatx4){0.f, 0.f, 0.f, 0.f} : acc[mt];
        acc[mt] = __builtin_amdgcn_mfma_f32_16x16x32_bf16(wf[mt][kc], b, c, 0, 0, 0);
      }
    }
    int t = t0 + ntile;
    #pragma unroll
    for (int mt = 0; mt < 4; ++mt) {
      float4v s = (acc[mt] + bias4[mt]) * C2;
      unsigned int d0 = cvt_pk_bf16(s[0], s[1]);
      unsigned int d1 = cvt_pk_bf16(s[2], s[3]);
      int gg2 = g * 4 + (lr >> 2);
      int lp  = lq * 16 + mt * 4 + (lr & 3);
      size_t base = (size_t)t * 16384 + (size_t)(gg2 * 1024 + w * 128 + lp);
      xp[base] = d0;          // pr=0: hcols lq*4+0,1
      xp[base + 64] = d1;     // pr=1: hcols lq*4+2,3
    }
  }
}

// ---------------------------------------------------------------------------
// Scan: 16 WGs (batch groups of 4) x 512 threads (8 waves, 2/SIMD).
// W_hh i8 per-row-scale, register-resident. h in i8 LDS, B-frag-linear
// layout hN[buf][kc*1024 + lane*16] (conflict-free ds_read_b128).
// Double-buffered, ONE barrier/step, 2-step unroll (static LDS bases).
// Schedule: ds_reads issue first post-barrier (sched_barrier pins), xp
// prefetch issues under the setprio(1)-wrapped MFMA burst. DPP
// row_shr:{4,8,12} bank-masked redistributes mt=1..3 accumulators so all
// 64 lanes share the tanh (4 elems/lane).
// ---------------------------------------------------------------------------
__global__ __launch_bounds__(512, 2)
void scan_kernel(const float* __restrict__ Whh, const unsigned int* __restrict__ xp,
                 const float* __restrict__ Who, const float* __restrict__ bho,
                 float* __restrict__ out)
{
  __shared__ __align__(16) unsigned char hN[2][8192];  // [buf][kc*1024 + lane*16]
  __shared__ float smax[8][4][16];
  __shared__ __align__(16) short hbf[16 * 520];

  const int tid = threadIdx.x;
  const int gg = blockIdx.x;                // batches gg*4 .. gg*4+3
  const int ws = tid >> 6, l = tid & 63;
  const int lr = l & 15, lq = l >> 4;
  const int quad = lr >> 2, bb = lr & 3;
  const float C2 = 2.885390081777927f;

  // ---- per-row |max| of W_hh (wave ws owns hcols ws*64..+63) ----
  float rmax[4];
  #pragma unroll
  for (int mt = 0; mt < 4; ++mt) {
    const float* row = Whh + (size_t)(ws * 64 + mt * 16 + lr) * HDIM + lq * 128;
    float m = 0.f;
    #pragma unroll 8
    for (int j = 0; j < 128; j += 4) {
      float4v v = *(const float4v*)(row + j);
      m = fmaxf(m, fmaxf(fmaxf(fabsf(v[0]), fabsf(v[1])), fmaxf(fabsf(v[2]), fabsf(v[3]))));
    }
    m = fmaxf(m, __shfl_xor(m, 16));
    m = fmaxf(m, __shfl_xor(m, 32));
    rmax[mt] = fmaxf(m, 1e-20f);
    if (lq == 0) smax[ws][mt][lr] = rmax[mt];
  }

  // ---- quantize W fragments (A operand): lane k = kc*64 + lq*16 + 0..15 ----
  int4v wq[8][4];
  #pragma unroll
  for (int mt = 0; mt < 4; ++mt) {
    float qs = 127.0f / rmax[mt];
    #pragma unroll
    for (int kc = 0; kc < 8; ++kc) {
      const float* src = Whh + (size_t)(ws * 64 + mt * 16 + lr) * HDIM + kc * 64 + lq * 16;
      int4v d;
      #pragma unroll
      for (int dw = 0; dw < 4; ++dw) {
        float4v v = *(const float4v*)(src + dw * 4);
        int b0 = (int)__builtin_rintf(v[0] * qs);
        int b1 = (int)__builtin_rintf(v[1] * qs);
        int b2 = (int)__builtin_rintf(v[2] * qs);
        int b3 = (int)__builtin_rintf(v[3] * qs);
        d[dw] = (b0 & 255) | ((b1 & 255) << 8) | ((b2 & 255) << 16) | (b3 << 24);
      }
      wq[kc][mt] = d;
    }
  }

  for (int i = tid; i < 2 * 8192 / 4; i += 512) ((int*)hN)[i] = 0;
  __syncthreads();

  // ---- per-lane dequant scales: lane's quadrant picks mt = quad ----
  float sc[4];
  #pragma unroll
  for (int r = 0; r < 4; ++r)
    sc[r] = smax[ws][quad][lq * 4 + r] * (C2 / 16129.0f);

  const unsigned int* xpb = xp + (size_t)(gg * 1024 + ws * 128 + l);
  // write addr: h[batch=bb][k = ws*64 + quad*16 + lq*4 .. +3]
  const int waddr = ws * 1024 + quad * 256 + bb * 16 + lq * 4;

  // ---- bootstrap: h(after xp(0)) = tanh(xp(0)) into buf0; load xp(1) ----
  unsigned int u0 = xpb[0], u1 = xpb[64];
  {
    unsigned int pk = tanh_pack4(__uint_as_float(u0 << 16), __uint_as_float(u0 & 0xffff0000u),
                                 __uint_as_float(u1 << 16), __uint_as_float(u1 & 0xffff0000u));
    *(unsigned int*)&hN[0][waddr] = pk;
  }
  u0 = xpb[16384]; u1 = xpb[16384 + 64];
  __syncthreads();

  const int4v zero4 = {0, 0, 0, 0};
  const unsigned int* qp = xpb + (size_t)2 * 16384;   // running prefetch ptr

  // One recurrence step: read rb, write wb; consumes (u0,u1); if PF,
  // prefetches the next xp pair and advances qp.
  auto do_step = [&](const unsigned char* __restrict__ rb,
                     unsigned char* __restrict__ wb, bool pf) {
    // 1) LDS b-frags first (lgkmcnt gates the first MFMA)
    int4v bfr[8];
    #pragma unroll
    for (int kc = 0; kc < 8; ++kc)
      bfr[kc] = *(const int4v*)(rb + kc * 1024 + l * 16);
    __builtin_amdgcn_sched_barrier(0);
    // 2) xp prefetch issues under the MFMA burst
    unsigned int un0, un1;
    if (pf) { un0 = qp[0]; un1 = qp[64]; qp += 16384; }
    // 3) MFMA burst, priority-boosted
    int4v acc[4];
    #pragma unroll
    for (int mt = 0; mt < 4; ++mt) acc[mt] = zero4;
    __builtin_amdgcn_s_setprio(1);
    #pragma unroll
    for (int kc = 0; kc < 8; ++kc)
      #pragma unroll
      for (int mt = 0; mt < 4; ++mt)
        acc[mt] = __builtin_amdgcn_mfma_i32_16x16x64_i8(wq[kc][mt], bfr[kc], acc[mt], 0, 0, 0);
    __builtin_amdgcn_s_setprio(0);
    // 4) DPP redistribute + dequant + xp + tanh + pack (4 elems/lane)
    int4v ap;
    #pragma unroll
    for (int d = 0; d < 4; ++d) {
      int r = acc[0][d];
      r = dpp_overlay<0x114, 0x2>(r, acc[1][d]);   // row_shr:4  -> lanes 4..7
      r = dpp_overlay<0x118, 0x4>(r, acc[2][d]);   // row_shr:8  -> lanes 8..11
      r = dpp_overlay<0x11C, 0x8>(r, acc[3][d]);   // row_shr:12 -> lanes 12..15
      ap[d] = r;
    }
    unsigned int pk = tanh_pack4(
        (float)ap[0] * sc[0] + __uint_as_float(u0 << 16),
        (float)ap[1] * sc[1] + __uint_as_float(u0 & 0xffff0000u),
        (float)ap[2] * sc[2] + __uint_as_float(u1 << 16),
        (float)ap[3] * sc[3] + __uint_as_float(u1 & 0xffff0000u));
    *(unsigned int*)(wb + waddr) = pk;
    __syncthreads();
    if (pf) { u0 = un0; u1 = un1; }
  };

  // steps t=1..4094 in pairs (static buffers), tail t=4095 (no prefetch)
  #pragma unroll 1
  for (int t = 1; t <= TDIM - 3; t += 2) {
    do_step(hN[0], hN[1], true);
    do_step(hN[1], hN[0], true);
  }
  do_step(hN[0], hN[1], false);
  // final h (after xp(4095)) is in buf 1

  // ---- hT (output 1) + bf16 h for projection (batch rows 0..3 valid) ----
  for (int i = tid; i < 16 * 512; i += 512) {
    int row = i >> 9, col = i & 511;
    float f = 0.f;
    if (row < 4) {
      int a = (col >> 6) * 1024 + ((col >> 4) & 3) * 256 + row * 16 + (col & 15);
      f = (float)((signed char)hN[1][a]) * (1.0f / 127.0f);
      out[(size_t)ODIM * BDIM + ((size_t)(gg * 4 + row)) * HDIM + col] = f;
    }
    hbf[row * 520 + col] = (short)f2bf(f);
  }
  __syncthreads();

  // ---- output projection: D[batch][o] = h[batch][:] . Who[o][:] ----
  floatx4 oacc;
  #pragma unroll
  for (int kc = 0; kc < 16; ++kc) {
    short8 a = *(const short8*)&hbf[lr * 520 + kc * 32 + lq * 8];
    int o = ws * 16 + lr;
    const float* src = Who + (size_t)o * HDIM + kc * 32 + lq * 8;
    float4v f0 = *(const float4v*)src;
    float4v f1 = *(const float4v*)(src + 4);
    short8 s;
    s[0] = (short)f2bf(f0[0]); s[1] = (short)f2bf(f0[1]);
    s[2] = (short)f2bf(f0[2]); s[3] = (short)f2bf(f0[3]);
    s[4] = (short)f2bf(f1[0]); s[5] = (short)f2bf(f1[1]);
    s[6] = (short)f2bf(f1[2]); s[7] = (short)f2bf(f1[3]);
    floatx4 c = (kc == 0) ? (floatx4){0.f, 0.f, 0.f, 0.f} : oacc;
    oacc = __builtin_amdgcn_mfma_f32_16x16x32_bf16(a, s, c, 0, 0, 0);
  }
  #pragma unroll
  for (int rr = 0; rr < 4; ++rr) {
    int row = lq * 4 + rr;             // = batch within group; valid < 4
    if (row < 4) {
      int o = ws * 16 + lr;
      out[((size_t)(gg * 4 + row)) * ODIM + o] = oacc[rr] + bho[o];
    }
  }
}

// ---------------------------------------------------------------------------
extern "C" void kernel_launch(void* const* d_in, const int* in_sizes, int n_in,
                              void* d_out, int out_size, void* d_ws, size_t ws_size,
                              hipStream_t stream) {
  const float* x   = (const float*)d_in[0];
  const float* bd  = (const float*)d_in[1];
  const float* Wih = (const float*)d_in[2];
  const float* bih = (const float*)d_in[3];
  const float* Whh = (const float*)d_in[4];
  const float* bhh = (const float*)d_in[5];
  const float* Who = (const float*)d_in[6];
  const float* bho = (const float*)d_in[7];
  float* out = (float*)d_out;
  unsigned int* xp = (unsigned int*)d_ws;   // T*B*H*2 = 268.4 MB

  prep_kernel<<<dim3(TDIM / 16, 4), 512, 0, stream>>>(x, bd, Wih, bih, bhh, xp);
  scan_kernel<<<dim3(16), 512, 0, stream>>>(Whh, xp, Who, bho, out);
}